// Round 6
// baseline (1255.437 us; speedup 1.0000x reference)
//
#include <hip/hip_runtime.h>
#include <hip/hip_bf16.h>
#include <cmath>

// ---------------------------------------------------------------------------
// TextEncoder: 4-layer post-LN transformer, B=2 N=2048 D=1024 H=16 dh=64 FF=4096
// R4: (1) GEMM epilogue: erff -> fast tanh-gelu (exp2+rcp, ~10 ops, |err|<1e-3).
//     (2) attn: P^T relayout via per-wave LDS (4x ds_write_b64 + 2x ds_read_b128
//         replaces 16 shfl + 8 select); defer-max (T13, thr=11 in exp2 domain)
//         skips O-rescale + cross-lane max on most kv-tiles.
// ---------------------------------------------------------------------------

typedef __attribute__((ext_vector_type(8))) short bf16x8;
typedef __attribute__((ext_vector_type(4))) float f32x4;
typedef __hip_bfloat16 bf16;

#define DEV static __device__ __forceinline__

DEV unsigned short f2b(float f) {
    bf16 h = __float2bfloat16(f);
    return *reinterpret_cast<unsigned short*>(&h);
}

DEV unsigned int pack_bf16(float lo, float hi) {
    return (unsigned int)f2b(lo) | ((unsigned int)f2b(hi) << 16);
}

// tanh-form gelu: max abs deviation from exact ~1e-3, ~10 VALU ops.
DEV float gelu_fast(float x) {
    float u = 0.7978845608028654f * fmaf(0.044715f * x, x * x, x);
    u = fminf(fmaxf(u, -15.f), 15.f);               // v_med3; keeps exp2 finite
    float t = __builtin_amdgcn_exp2f(u * 2.8853900817779268f);  // e^(2u)
    float th = (t - 1.0f) * __builtin_amdgcn_rcpf(t + 1.0f);    // tanh(u)
    return 0.5f * x * (1.0f + th);
}

DEV void gload_lds16(const bf16* g, bf16* l) {
    __builtin_amdgcn_global_load_lds(
        (const __attribute__((address_space(1))) void*)g,
        (__attribute__((address_space(3))) void*)l, 16, 0, 0);
}

// ---- weight transpose + cast: Wt[l][n][k] = (bf16) W[l][k][n] --------------
__global__ __launch_bounds__(256) void transpose_cast(const float* __restrict__ W,
                                                      bf16* __restrict__ Wt,
                                                      int K, int Nm) {
    __shared__ float tile[32][33];
    const int l = blockIdx.z;
    const float* Wl = W + (size_t)l * K * Nm;
    bf16* Wtl = Wt + (size_t)l * K * Nm;
    const int n0 = blockIdx.x * 32, k0 = blockIdx.y * 32;
    const int tx = threadIdx.x, ty = threadIdx.y;
#pragma unroll
    for (int i = 0; i < 4; ++i)
        tile[ty + 8 * i][tx] = Wl[(size_t)(k0 + ty + 8 * i) * Nm + n0 + tx];
    __syncthreads();
#pragma unroll
    for (int i = 0; i < 4; ++i)
        Wtl[(size_t)(n0 + ty + 8 * i) * K + k0 + tx] = __float2bfloat16(tile[tx][ty + 8 * i]);
}

// ---- V transpose: qkv[b,n,2048+h*64+d] -> vtg[(b*16+h)*64+d][n]  (bf16) ----
__global__ __launch_bounds__(256) void vtrans(const bf16* __restrict__ qkv,
                                              bf16* __restrict__ vtg, int N) {
    __shared__ bf16 tile[32][33];
    const int bh = blockIdx.z, b = bh >> 4, h = bh & 15;
    const int n0 = blockIdx.x * 32, d0 = blockIdx.y * 32;
    const int tx = threadIdx.x, ty = threadIdx.y;
    const bf16* src = qkv + (size_t)(b * N + n0) * 3072 + 2048 + h * 64 + d0;
#pragma unroll
    for (int i = 0; i < 4; ++i)
        tile[ty + 8 * i][tx] = src[(size_t)(ty + 8 * i) * 3072 + tx];
    __syncthreads();
    bf16* dst = vtg + ((size_t)bh * 64 + d0) * N + n0;
#pragma unroll
    for (int i = 0; i < 4; ++i)
        dst[(size_t)(ty + 8 * i) * N + tx] = tile[tx][ty + 8 * i];
}

// ---- elementwise fp32 -> bf16 ----------------------------------------------
__global__ __launch_bounds__(256) void cast_bf16_k(const float* __restrict__ in,
                                                   bf16* __restrict__ out, int n4) {
    int i = blockIdx.x * 256 + threadIdx.x;
    if (i >= n4) return;
    float4 v = reinterpret_cast<const float4*>(in)[i];
    ushort4 o = { f2b(v.x), f2b(v.y), f2b(v.z), f2b(v.w) };
    reinterpret_cast<ushort4*>(out)[i] = o;
}

// ---- bf16 MFMA GEMM (m97 pattern): C[M,Nm] = A[M,K] @ Bt[Nm,K]^T + bias ----
// 1D grid with XCD-chunked swizzle (nwg % 8 == 0 for all our shapes).
template <int EPI>
__global__ __launch_bounds__(256) void gemm_bf16(const bf16* __restrict__ A,
                                                 const bf16* __restrict__ Bt,
                                                 const float* __restrict__ bias,
                                                 void* __restrict__ Cout,
                                                 int M, int Nm, int K, int nbx) {
    __shared__ bf16 As[128][64];  // linear: required by global_load_lds
    __shared__ bf16 Bs[128][64];
    const int nwg = gridDim.x;
    int id = blockIdx.x;
    if ((nwg & 7) == 0) id = (id & 7) * (nwg >> 3) + (id >> 3);  // XCD-chunked
    const int m0 = (id / nbx) * 128, n0 = (id % nbx) * 128;
    const int t = threadIdx.x, w = t >> 6, lane = t & 63;
    const int wr = (w >> 1) * 64, wc = (w & 1) * 64;
    const int lr = lane & 15, lg = lane >> 4;
    const int srowbase = w * 32;
    const int slrow = lane >> 3;
    const int scol = (lane & 7) * 8;

    f32x4 acc[4][4] = {};

    for (int k0 = 0; k0 < K; k0 += 64) {
        __syncthreads();
#pragma unroll
        for (int p = 0; p < 4; ++p) {
            const int r = srowbase + p * 8;
            gload_lds16(A + (size_t)(m0 + r + slrow) * K + k0 + scol, &As[r][0]);
            gload_lds16(Bt + (size_t)(n0 + r + slrow) * K + k0 + scol, &Bs[r][0]);
        }
        __syncthreads();
#pragma unroll
        for (int kk = 0; kk < 2; ++kk) {
            const int lk = kk * 32 + lg * 8;
            bf16x8 a[4], b[4];
#pragma unroll
            for (int m = 0; m < 4; ++m)
                a[m] = *reinterpret_cast<const bf16x8*>(&As[wr + m * 16 + lr][lk]);
#pragma unroll
            for (int n = 0; n < 4; ++n)
                b[n] = *reinterpret_cast<const bf16x8*>(&Bs[wc + n * 16 + lr][lk]);
#pragma unroll
            for (int m = 0; m < 4; ++m)
#pragma unroll
                for (int n = 0; n < 4; ++n)
                    acc[m][n] = __builtin_amdgcn_mfma_f32_16x16x32_bf16(a[m], b[n], acc[m][n], 0, 0, 0);
        }
    }

#pragma unroll
    for (int n = 0; n < 4; ++n) {
        const int col = n0 + wc + n * 16 + lr;
        const float bc = bias[col];
#pragma unroll
        for (int m = 0; m < 4; ++m) {
            const int row = m0 + wr + m * 16 + lg * 4;
#pragma unroll
            for (int j = 0; j < 4; ++j) {
                float v = acc[m][n][j] + bc;
                if (EPI >= 1) v = gelu_fast(v);
                if (EPI == 2)
                    reinterpret_cast<float*>(Cout)[(size_t)(row + j) * Nm + col] = v;
                else
                    reinterpret_cast<bf16*>(Cout)[(size_t)(row + j) * Nm + col] = __float2bfloat16(v);
            }
        }
    }
}

// ---- flash attention, swapped-operand form ---------------------------------
// grid 1D (N/64)*(B*H) swizzled; block 256 (4 waves); each wave owns 16 q-rows.
// S^T = mfma(K, Q): lane holds q=lr, kv=16c+4lg+j -> lane-local softmax.
// PV: O^T = mfma(V^T, P^T); P^T routed through per-wave LDS tile Ps[q][kv].
__global__ __launch_bounds__(256) void attn_fwd(const bf16* __restrict__ qkv,
                                                const bf16* __restrict__ vtg,
                                                float* __restrict__ o, int N) {
    __shared__ bf16 Ks[64][72];      // K tile [kv][dh], padded
    __shared__ bf16 Vs[64][72];      // V^T tile [dh][kv], padded
    __shared__ bf16 Ps[4][16][72];   // per-wave P [q][kv], padded
    const int nwg = gridDim.x, nbx = N / 64;
    int id = blockIdx.x;
    id = (id & 7) * (nwg >> 3) + (id >> 3);  // XCD-chunked: 4 heads' K/V per L2
    const int bh = id / nbx, b = bh >> 4, h = bh & 15;
    const int q0 = (id % nbx) * 64;
    const int t = threadIdx.x, w = t >> 6, lane = t & 63;
    const int lr = lane & 15, lg = lane >> 4;
    const bf16* base = qkv + (size_t)b * N * 3072;
    const bf16* vbase = vtg + (size_t)bh * 64 * N;

    // Q as B-operand: col q = lr, k = 32f + 8lg + i
    bf16x8 qf[2];
    {
        const bf16* qp = base + (size_t)(q0 + w * 16 + lr) * 3072 + h * 64 + lg * 8;
        qf[0] = *reinterpret_cast<const bf16x8*>(qp);
        qf[1] = *reinterpret_cast<const bf16x8*>(qp + 32);
    }

    float mrow = -INFINITY, lrow = 0.f;
    f32x4 oacc[4] = {};
    const float scale2 = 0.03125f * 1.44269504088896340736f;  // embedDim^-0.5 * log2(e)
    const int srow = t >> 2, scol = (t & 3) * 8;

    for (int kv0 = 0; kv0 < N; kv0 += 64) {
        __syncthreads();
        {   // stage K [kv][dh] and V^T [dh][kv]
            const bf16* ksrc = base + (size_t)(kv0 + srow) * 3072 + 1024 + h * 64 + scol;
            *reinterpret_cast<uint4*>(&Ks[srow][scol])      = *reinterpret_cast<const uint4*>(ksrc);
            *reinterpret_cast<uint4*>(&Ks[srow][scol + 32]) = *reinterpret_cast<const uint4*>(ksrc + 32);
            const bf16* vsrc = vbase + (size_t)srow * N + kv0 + scol;
            *reinterpret_cast<uint4*>(&Vs[srow][scol])      = *reinterpret_cast<const uint4*>(vsrc);
            *reinterpret_cast<uint4*>(&Vs[srow][scol + 32]) = *reinterpret_cast<const uint4*>(vsrc + 32);
        }
        __syncthreads();

        // S^T[kv][q] = K @ Q^T : A = K-frag (rows kv), B = Q-frag (cols q)
        f32x4 st[4] = {};
#pragma unroll
        for (int f = 0; f < 2; ++f)
#pragma unroll
            for (int c = 0; c < 4; ++c) {
                bf16x8 ka = *reinterpret_cast<const bf16x8*>(&Ks[c * 16 + lr][f * 32 + lg * 8]);
                st[c] = __builtin_amdgcn_mfma_f32_16x16x32_bf16(ka, qf[f], st[c], 0, 0, 0);
            }

        // lane-local max over this lane's 16 kv values (exp2 domain)
        float smax = st[0][0];
#pragma unroll
        for (int c = 0; c < 4; ++c)
#pragma unroll
            for (int j = 0; j < 4; ++j) smax = fmaxf(smax, st[c][j]);
        const float tilemax = smax * scale2;

        // defer-max (T13): rescale only when some lane exceeds mrow by >11
        // (P bounded by 2^11 = 2048 -- fine in bf16/fp32 accumulation)
        if (!__all(tilemax - mrow <= 11.0f)) {
            float tm = fmaxf(tilemax, __shfl_xor(tilemax, 16, 64));
            tm = fmaxf(tm, __shfl_xor(tm, 32, 64));   // uniform across lg for fixed q
            const float mnew = fmaxf(mrow, tm);
            const float al = __builtin_amdgcn_exp2f(mrow - mnew);
            mrow = mnew;
            lrow *= al;
#pragma unroll
            for (int c = 0; c < 4; ++c)
#pragma unroll
                for (int j = 0; j < 4; ++j) oacc[c][j] *= al;
        }

        float p[4][4];
        float psum = 0.f;
#pragma unroll
        for (int c = 0; c < 4; ++c)
#pragma unroll
            for (int j = 0; j < 4; ++j) {
                p[c][j] = __builtin_amdgcn_exp2f(fmaf(st[c][j], scale2, -mrow));
                psum += p[c][j];
            }
        psum += __shfl_xor(psum, 16, 64);
        psum += __shfl_xor(psum, 32, 64);
        lrow += psum;

        // write P to per-wave LDS: lane holds P[q=lr][kv=16c+4lg+{0..3}]
#pragma unroll
        for (int c = 0; c < 4; ++c) {
            uint2 pr = { pack_bf16(p[c][0], p[c][1]), pack_bf16(p[c][2], p[c][3]) };
            *reinterpret_cast<uint2*>(&Ps[w][lr][c * 16 + lg * 4]) = pr;
        }
        asm volatile("s_waitcnt lgkmcnt(0)" ::: "memory");  // in-wave write->read
        __builtin_amdgcn_sched_barrier(0);

        // O^T += V^T @ P^T : B-frag col q=lr, k = f*32+lg*8+i -> Ps[lr][...]
#pragma unroll
        for (int f = 0; f < 2; ++f) {
            bf16x8 pb = *reinterpret_cast<const bf16x8*>(&Ps[w][lr][f * 32 + lg * 8]);
#pragma unroll
            for (int c = 0; c < 4; ++c) {
                bf16x8 va = *reinterpret_cast<const bf16x8*>(&Vs[c * 16 + lr][f * 32 + lg * 8]);
                oacc[c] = __builtin_amdgcn_mfma_f32_16x16x32_bf16(va, pb, oacc[c], 0, 0, 0);
            }
        }
    }

    // O^T layout: col q = lr, row d = 16c + 4lg + j -> float4 stores
    const float linv = 1.f / lrow;
    float* op = o + ((size_t)b * N + q0 + w * 16 + lr) * 1024 + h * 64;
#pragma unroll
    for (int c = 0; c < 4; ++c) {
        float4 v = { oacc[c][0] * linv, oacc[c][1] * linv,
                     oacc[c][2] * linv, oacc[c][3] * linv };
        *reinterpret_cast<float4*>(op + c * 16 + lg * 4) = v;
    }
}

// ---- fused residual + LayerNorm (fp32), optional bf16 copy -----------------
__global__ __launch_bounds__(256) void ln_res(const float* __restrict__ a,
                                              const float* __restrict__ r,
                                              const float* __restrict__ g,
                                              const float* __restrict__ be,
                                              float* __restrict__ y,
                                              bf16* __restrict__ yb) {
    const int row = blockIdx.x, t = threadIdx.x;
    float4 va = reinterpret_cast<const float4*>(a + (size_t)row * 1024)[t];
    float4 vr = reinterpret_cast<const float4*>(r + (size_t)row * 1024)[t];
    float v0 = va.x + vr.x, v1 = va.y + vr.y, v2 = va.z + vr.z, v3 = va.w + vr.w;
    float s1 = v0 + v1 + v2 + v3;
    float s2 = v0 * v0 + v1 * v1 + v2 * v2 + v3 * v3;
#pragma unroll
    for (int m = 1; m < 64; m <<= 1) {
        s1 += __shfl_xor(s1, m, 64);
        s2 += __shfl_xor(s2, m, 64);
    }
    __shared__ float ws1[4], ws2[4];
    if ((t & 63) == 0) { ws1[t >> 6] = s1; ws2[t >> 6] = s2; }
    __syncthreads();
    s1 = ws1[0] + ws1[1] + ws1[2] + ws1[3];
    s2 = ws2[0] + ws2[1] + ws2[2] + ws2[3];
    const float mean = s1 * (1.f / 1024.f);
    const float var = s2 * (1.f / 1024.f) - mean * mean;
    const float rstd = rsqrtf(var + 1e-5f);
    float4 gg = reinterpret_cast<const float4*>(g)[t];
    float4 bb = reinterpret_cast<const float4*>(be)[t];
    float o0 = (v0 - mean) * rstd * gg.x + bb.x;
    float o1 = (v1 - mean) * rstd * gg.y + bb.y;
    float o2 = (v2 - mean) * rstd * gg.z + bb.z;
    float o3 = (v3 - mean) * rstd * gg.w + bb.w;
    float4 out = { o0, o1, o2, o3 };
    reinterpret_cast<float4*>(y + (size_t)row * 1024)[t] = out;
    if (yb) {
        ushort4 ob = { f2b(o0), f2b(o1), f2b(o2), f2b(o3) };
        reinterpret_cast<ushort4*>(yb + (size_t)row * 1024)[t] = ob;
    }
}

// ---------------------------------------------------------------------------
extern "C" void kernel_launch(void* const* d_in, const int* in_sizes, int n_in,
                              void* d_out, int out_size, void* d_ws, size_t ws_size,
                              hipStream_t stream) {
    const float* x_in = (const float*)d_in[0];
    const float* Wqkv = (const float*)d_in[1];
    const float* bqkv = (const float*)d_in[2];
    const float* W1   = (const float*)d_in[3];
    const float* b1   = (const float*)d_in[4];
    const float* W2   = (const float*)d_in[5];
    const float* b2   = (const float*)d_in[6];
    const float* g1   = (const float*)d_in[7];
    const float* be1  = (const float*)d_in[8];
    const float* g2   = (const float*)d_in[9];
    const float* be2  = (const float*)d_in[10];

    const int Bv = 2, N = 2048, L = 4, Hh = 16;
    const int R = Bv * N;  // 4096 token rows

    char* p = (char*)d_ws;
    auto alloc = [&](size_t bytes) { char* r = p; p += (bytes + 255) & ~(size_t)255; return r; };
    bf16*  Wqkvt = (bf16*)alloc((size_t)L * 3072 * 1024 * 2);
    bf16*  W1t   = (bf16*)alloc((size_t)L * 4096 * 1024 * 2);
    bf16*  W2t   = (bf16*)alloc((size_t)L * 1024 * 4096 * 2);
    bf16*  xb    = (bf16*)alloc((size_t)R * 1024 * 2);
    bf16*  qkvb  = (bf16*)alloc((size_t)R * 3072 * 2);
    float* obuf  = (float*)alloc((size_t)R * 1024 * 4);
    float* hbuf  = (float*)alloc((size_t)R * 1024 * 4);
    bf16*  hb    = (bf16*)alloc((size_t)R * 1024 * 2);
    bf16*  f1b   = (bf16*)alloc((size_t)R * 4096 * 2);
    float* xcur  = (float*)alloc((size_t)R * 1024 * 4);
    float* f2buf = obuf;        // obuf dead after LN1 -> reuse for f2
    bf16*  vtg   = (bf16*)hbuf; // 8.4MB V^T; hbuf region dead during qkv-gemm/attn

    transpose_cast<<<dim3(3072 / 32, 1024 / 32, L), dim3(32, 8), 0, stream>>>(Wqkv, Wqkvt, 1024, 3072);
    transpose_cast<<<dim3(4096 / 32, 1024 / 32, L), dim3(32, 8), 0, stream>>>(W1, W1t, 1024, 4096);
    transpose_cast<<<dim3(1024 / 32, 4096 / 32, L), dim3(32, 8), 0, stream>>>(W2, W2t, 4096, 1024);
    cast_bf16_k<<<(R * 1024 / 4 + 255) / 256, 256, 0, stream>>>(x_in, xb, R * 1024 / 4);

    const float* xres = x_in;
    for (int l = 0; l < L; ++l) {
        // qkv = x @ Wqkv + bqkv  -> bf16
        gemm_bf16<0><<<(3072 / 128) * (R / 128), 256, 0, stream>>>(
            xb, Wqkvt + (size_t)l * 3072 * 1024, bqkv + l * 3072, qkvb, R, 3072, 1024, 3072 / 128);
        // V^T per (b,h): [dh][N]
        vtrans<<<dim3(N / 32, 2, Bv * Hh), dim3(32, 8), 0, stream>>>(qkvb, vtg, N);
        // o = softmax(q k^T / 32) v
        attn_fwd<<<(N / 64) * (Bv * Hh), 256, 0, stream>>>(qkvb, vtg, obuf, N);
        // h = LN(o + x)   (overwrites vtg region -- attn already done)
        ln_res<<<R, 256, 0, stream>>>(obuf, xres, g1 + l * 1024, be1 + l * 1024, hbuf, hb);
        // f1 = gelu(h @ W1 + b1) -> bf16
        gemm_bf16<1><<<(4096 / 128) * (R / 128), 256, 0, stream>>>(
            hb, W1t + (size_t)l * 4096 * 1024, b1 + l * 4096, f1b, R, 4096, 1024, 4096 / 128);
        // f2 = gelu(f1 @ W2 + b2) -> fp32
        gemm_bf16<2><<<(1024 / 128) * (R / 128), 256, 0, stream>>>(
            f1b, W2t + (size_t)l * 1024 * 4096, b2 + l * 1024, f2buf, R, 1024, 4096, 1024 / 128);
        // x = LN(f2 + h), also emit bf16 copy for next layer's GEMM
        float* xn = (l == L - 1) ? (float*)d_out : xcur;
        ln_res<<<R, 256, 0, stream>>>(f2buf, hbuf, g2 + l * 1024, be2 + l * 1024, xn, xb);
        xres = xn;
    }
}

// Round 7
// 1251.748 us; speedup vs baseline: 1.0029x; 1.0029x over previous
//
#include <hip/hip_runtime.h>
#include <hip/hip_bf16.h>
#include <cmath>

// ---------------------------------------------------------------------------
// TextEncoder: 4-layer post-LN transformer, B=2 N=2048 D=1024 H=16 dh=64 FF=4096
// R4: (1) GEMM epilogue: erff -> fast tanh-gelu (exp2+rcp, ~10 ops, |err|<1e-3).
//     (2) attn: P^T relayout via per-wave LDS (4x ds_write_b64 + 2x ds_read_b128
//         replaces 16 shfl + 8 select); defer-max (T13, thr=11 in exp2 domain)
//         skips O-rescale + cross-lane max on most kv-tiles.
// ---------------------------------------------------------------------------

typedef __attribute__((ext_vector_type(8))) short bf16x8;
typedef __attribute__((ext_vector_type(4))) float f32x4;
typedef __hip_bfloat16 bf16;

#define DEV static __device__ __forceinline__

DEV unsigned short f2b(float f) {
    bf16 h = __float2bfloat16(f);
    return *reinterpret_cast<unsigned short*>(&h);
}

DEV unsigned int pack_bf16(float lo, float hi) {
    return (unsigned int)f2b(lo) | ((unsigned int)f2b(hi) << 16);
}

// tanh-form gelu: max abs deviation from exact ~1e-3, ~10 VALU ops.
DEV float gelu_fast(float x) {
    float u = 0.7978845608028654f * fmaf(0.044715f * x, x * x, x);
    u = fminf(fmaxf(u, -15.f), 15.f);               // v_med3; keeps exp2 finite
    float t = __builtin_amdgcn_exp2f(u * 2.8853900817779268f);  // e^(2u)
    float th = (t - 1.0f) * __builtin_amdgcn_rcpf(t + 1.0f);    // tanh(u)
    return 0.5f * x * (1.0f + th);
}

DEV void gload_lds16(const bf16* g, bf16* l) {
    __builtin_amdgcn_global_load_lds(
        (const __attribute__((address_space(1))) void*)g,
        (__attribute__((address_space(3))) void*)l, 16, 0, 0);
}

// ---- weight transpose + cast: Wt[l][n][k] = (bf16) W[l][k][n] --------------
__global__ __launch_bounds__(256) void transpose_cast(const float* __restrict__ W,
                                                      bf16* __restrict__ Wt,
                                                      int K, int Nm) {
    __shared__ float tile[32][33];
    const int l = blockIdx.z;
    const float* Wl = W + (size_t)l * K * Nm;
    bf16* Wtl = Wt + (size_t)l * K * Nm;
    const int n0 = blockIdx.x * 32, k0 = blockIdx.y * 32;
    const int tx = threadIdx.x, ty = threadIdx.y;
#pragma unroll
    for (int i = 0; i < 4; ++i)
        tile[ty + 8 * i][tx] = Wl[(size_t)(k0 + ty + 8 * i) * Nm + n0 + tx];
    __syncthreads();
#pragma unroll
    for (int i = 0; i < 4; ++i)
        Wtl[(size_t)(n0 + ty + 8 * i) * K + k0 + tx] = __float2bfloat16(tile[tx][ty + 8 * i]);
}

// ---- V transpose: qkv[b,n,2048+h*64+d] -> vtg[(b*16+h)*64+d][n]  (bf16) ----
__global__ __launch_bounds__(256) void vtrans(const bf16* __restrict__ qkv,
                                              bf16* __restrict__ vtg, int N) {
    __shared__ bf16 tile[32][33];
    const int bh = blockIdx.z, b = bh >> 4, h = bh & 15;
    const int n0 = blockIdx.x * 32, d0 = blockIdx.y * 32;
    const int tx = threadIdx.x, ty = threadIdx.y;
    const bf16* src = qkv + (size_t)(b * N + n0) * 3072 + 2048 + h * 64 + d0;
#pragma unroll
    for (int i = 0; i < 4; ++i)
        tile[ty + 8 * i][tx] = src[(size_t)(ty + 8 * i) * 3072 + tx];
    __syncthreads();
    bf16* dst = vtg + ((size_t)bh * 64 + d0) * N + n0;
#pragma unroll
    for (int i = 0; i < 4; ++i)
        dst[(size_t)(ty + 8 * i) * N + tx] = tile[tx][ty + 8 * i];
}

// ---- elementwise fp32 -> bf16 ----------------------------------------------
__global__ __launch_bounds__(256) void cast_bf16_k(const float* __restrict__ in,
                                                   bf16* __restrict__ out, int n4) {
    int i = blockIdx.x * 256 + threadIdx.x;
    if (i >= n4) return;
    float4 v = reinterpret_cast<const float4*>(in)[i];
    ushort4 o = { f2b(v.x), f2b(v.y), f2b(v.z), f2b(v.w) };
    reinterpret_cast<ushort4*>(out)[i] = o;
}

// ---- bf16 MFMA GEMM (m97 pattern): C[M,Nm] = A[M,K] @ Bt[Nm,K]^T + bias ----
// 1D grid with XCD-chunked swizzle (nwg % 8 == 0 for all our shapes).
template <int EPI>
__global__ __launch_bounds__(256) void gemm_bf16(const bf16* __restrict__ A,
                                                 const bf16* __restrict__ Bt,
                                                 const float* __restrict__ bias,
                                                 void* __restrict__ Cout,
                                                 int M, int Nm, int K, int nbx) {
    __shared__ bf16 As[128][64];  // linear: required by global_load_lds
    __shared__ bf16 Bs[128][64];
    const int nwg = gridDim.x;
    int id = blockIdx.x;
    if ((nwg & 7) == 0) id = (id & 7) * (nwg >> 3) + (id >> 3);  // XCD-chunked
    const int m0 = (id / nbx) * 128, n0 = (id % nbx) * 128;
    const int t = threadIdx.x, w = t >> 6, lane = t & 63;
    const int wr = (w >> 1) * 64, wc = (w & 1) * 64;
    const int lr = lane & 15, lg = lane >> 4;
    const int srowbase = w * 32;
    const int slrow = lane >> 3;
    const int scol = (lane & 7) * 8;

    f32x4 acc[4][4] = {};

    for (int k0 = 0; k0 < K; k0 += 64) {
        __syncthreads();
#pragma unroll
        for (int p = 0; p < 4; ++p) {
            const int r = srowbase + p * 8;
            gload_lds16(A + (size_t)(m0 + r + slrow) * K + k0 + scol, &As[r][0]);
            gload_lds16(Bt + (size_t)(n0 + r + slrow) * K + k0 + scol, &Bs[r][0]);
        }
        __syncthreads();
#pragma unroll
        for (int kk = 0; kk < 2; ++kk) {
            const int lk = kk * 32 + lg * 8;
            bf16x8 a[4], b[4];
#pragma unroll
            for (int m = 0; m < 4; ++m)
                a[m] = *reinterpret_cast<const bf16x8*>(&As[wr + m * 16 + lr][lk]);
#pragma unroll
            for (int n = 0; n < 4; ++n)
                b[n] = *reinterpret_cast<const bf16x8*>(&Bs[wc + n * 16 + lr][lk]);
#pragma unroll
            for (int m = 0; m < 4; ++m)
#pragma unroll
                for (int n = 0; n < 4; ++n)
                    acc[m][n] = __builtin_amdgcn_mfma_f32_16x16x32_bf16(a[m], b[n], acc[m][n], 0, 0, 0);
        }
    }

#pragma unroll
    for (int n = 0; n < 4; ++n) {
        const int col = n0 + wc + n * 16 + lr;
        const float bc = bias[col];
#pragma unroll
        for (int m = 0; m < 4; ++m) {
            const int row = m0 + wr + m * 16 + lg * 4;
#pragma unroll
            for (int j = 0; j < 4; ++j) {
                float v = acc[m][n][j] + bc;
                if (EPI >= 1) v = gelu_fast(v);
                if (EPI == 2)
                    reinterpret_cast<float*>(Cout)[(size_t)(row + j) * Nm + col] = v;
                else
                    reinterpret_cast<bf16*>(Cout)[(size_t)(row + j) * Nm + col] = __float2bfloat16(v);
            }
        }
    }
}

// ---- flash attention, swapped-operand form ---------------------------------
// grid 1D (N/64)*(B*H) swizzled; block 256 (4 waves); each wave owns 16 q-rows.
// S^T = mfma(K, Q): lane holds q=lr, kv=16c+4lg+j -> lane-local softmax.
// PV: O^T = mfma(V^T, P^T); P^T routed through per-wave LDS tile Ps[q][kv].
__global__ __launch_bounds__(256) void attn_fwd(const bf16* __restrict__ qkv,
                                                const bf16* __restrict__ vtg,
                                                float* __restrict__ o, int N) {
    __shared__ bf16 Ks[64][72];      // K tile [kv][dh], padded
    __shared__ bf16 Vs[64][72];      // V^T tile [dh][kv], padded
    __shared__ bf16 Ps[4][16][72];   // per-wave P [q][kv], padded
    const int nwg = gridDim.x, nbx = N / 64;
    int id = blockIdx.x;
    id = (id & 7) * (nwg >> 3) + (id >> 3);  // XCD-chunked: 4 heads' K/V per L2
    const int bh = id / nbx, b = bh >> 4, h = bh & 15;
    const int q0 = (id % nbx) * 64;
    const int t = threadIdx.x, w = t >> 6, lane = t & 63;
    const int lr = lane & 15, lg = lane >> 4;
    const bf16* base = qkv + (size_t)b * N * 3072;
    const bf16* vbase = vtg + (size_t)bh * 64 * N;

    // Q as B-operand: col q = lr, k = 32f + 8lg + i
    bf16x8 qf[2];
    {
        const bf16* qp = base + (size_t)(q0 + w * 16 + lr) * 3072 + h * 64 + lg * 8;
        qf[0] = *reinterpret_cast<const bf16x8*>(qp);
        qf[1] = *reinterpret_cast<const bf16x8*>(qp + 32);
    }

    float mrow = -INFINITY, lrow = 0.f;
    f32x4 oacc[4] = {};
    const float scale2 = 0.03125f * 1.44269504088896340736f;  // embedDim^-0.5 * log2(e)
    const int srow = t >> 2, scol = (t & 3) * 8;

    for (int kv0 = 0; kv0 < N; kv0 += 64) {
        __syncthreads();
        {   // stage K [kv][dh] and V^T [dh][kv]
            const bf16* ksrc = base + (size_t)(kv0 + srow) * 3072 + 1024 + h * 64 + scol;
            *reinterpret_cast<uint4*>(&Ks[srow][scol])      = *reinterpret_cast<const uint4*>(ksrc);
            *reinterpret_cast<uint4*>(&Ks[srow][scol + 32]) = *reinterpret_cast<const uint4*>(ksrc + 32);
            const bf16* vsrc = vbase + (size_t)srow * N + kv0 + scol;
            *reinterpret_cast<uint4*>(&Vs[srow][scol])      = *reinterpret_cast<const uint4*>(vsrc);
            *reinterpret_cast<uint4*>(&Vs[srow][scol + 32]) = *reinterpret_cast<const uint4*>(vsrc + 32);
        }
        __syncthreads();

        // S^T[kv][q] = K @ Q^T : A = K-frag (rows kv), B = Q-frag (cols q)
        f32x4 st[4] = {};
#pragma unroll
        for (int f = 0; f < 2; ++f)
#pragma unroll
            for (int c = 0; c < 4; ++c) {
                bf16x8 ka = *reinterpret_cast<const bf16x8*>(&Ks[c * 16 + lr][f * 32 + lg * 8]);
                st[c] = __builtin_amdgcn_mfma_f32_16x16x32_bf16(ka, qf[f], st[c], 0, 0, 0);
            }

        // lane-local max over this lane's 16 kv values (exp2 domain)
        float smax = st[0][0];
#pragma unroll
        for (int c = 0; c < 4; ++c)
#pragma unroll
            for (int j = 0; j < 4; ++j) smax = fmaxf(smax, st[c][j]);
        const float tilemax = smax * scale2;

        // defer-max (T13): rescale only when some lane exceeds mrow by >11
        // (P bounded by 2^11 = 2048 -- fine in bf16/fp32 accumulation)
        if (!__all(tilemax - mrow <= 11.0f)) {
            float tm = fmaxf(tilemax, __shfl_xor(tilemax, 16, 64));
            tm = fmaxf(tm, __shfl_xor(tm, 32, 64));   // uniform across lg for fixed q
            const float mnew = fmaxf(mrow, tm);
            const float al = __builtin_amdgcn_exp2f(mrow - mnew);
            mrow = mnew;
            lrow *= al;
#pragma unroll
            for (int c = 0; c < 4; ++c)
#pragma unroll
                for (int j = 0; j < 4; ++j) oacc[c][j] *= al;
        }

        float p[4][4];
        float psum = 0.f;
#pragma unroll
        for (int c = 0; c < 4; ++c)
#pragma unroll
            for (int j = 0; j < 4; ++j) {
                p[c][j] = __builtin_amdgcn_exp2f(fmaf(st[c][j], scale2, -mrow));
                psum += p[c][j];
            }
        psum += __shfl_xor(psum, 16, 64);
        psum += __shfl_xor(psum, 32, 64);
        lrow += psum;

        // write P to per-wave LDS: lane holds P[q=lr][kv=16c+4lg+{0..3}]
#pragma unroll
        for (int c = 0; c < 4; ++c) {
            uint2 pr = { pack_bf16(p[c][0], p[c][1]), pack_bf16(p[c][2], p[c][3]) };
            *reinterpret_cast<uint2*>(&Ps[w][lr][c * 16 + lg * 4]) = pr;
        }
        asm volatile("s_waitcnt lgkmcnt(0)" ::: "memory");  // in-wave write->read
        __builtin_amdgcn_sched_barrier(0);

        // O^T += V^T @ P^T : B-frag col q=lr, k = f*32+lg*8+i -> Ps[lr][...]
#pragma unroll
        for (int f = 0; f < 2; ++f) {
            bf16x8 pb = *reinterpret_cast<const bf16x8*>(&Ps[w][lr][f * 32 + lg * 8]);
#pragma unroll
            for (int c = 0; c < 4; ++c) {
                bf16x8 va = *reinterpret_cast<const bf16x8*>(&Vs[c * 16 + lr][f * 32 + lg * 8]);
                oacc[c] = __builtin_amdgcn_mfma_f32_16x16x32_bf16(va, pb, oacc[c], 0, 0, 0);
            }
        }
    }

    // O^T layout: col q = lr, row d = 16c + 4lg + j -> float4 stores
    const float linv = 1.f / lrow;
    float* op = o + ((size_t)b * N + q0 + w * 16 + lr) * 1024 + h * 64;
#pragma unroll
    for (int c = 0; c < 4; ++c) {
        float4 v = { oacc[c][0] * linv, oacc[c][1] * linv,
                     oacc[c][2] * linv, oacc[c][3] * linv };
        *reinterpret_cast<float4*>(op + c * 16 + lg * 4) = v;
    }
}

// ---- fused residual + LayerNorm (fp32), optional bf16 copy -----------------
__global__ __launch_bounds__(256) void ln_res(const float* __restrict__ a,
                                              const float* __restrict__ r,
                                              const float* __restrict__ g,
                                              const float* __restrict__ be,
                                              float* __restrict__ y,
                                              bf16* __restrict__ yb) {
    const int row = blockIdx.x, t = threadIdx.x;
    float4 va = reinterpret_cast<const float4*>(a + (size_t)row * 1024)[t];
    float4 vr = reinterpret_cast<const float4*>(r + (size_t)row * 1024)[t];
    float v0 = va.x + vr.x, v1 = va.y + vr.y, v2 = va.z + vr.z, v3 = va.w + vr.w;
    float s1 = v0 + v1 + v2 + v3;
    float s2 = v0 * v0 + v1 * v1 + v2 * v2 + v3 * v3;
#pragma unroll
    for (int m = 1; m < 64; m <<= 1) {
        s1 += __shfl_xor(s1, m, 64);
        s2 += __shfl_xor(s2, m, 64);
    }
    __shared__ float ws1[4], ws2[4];
    if ((t & 63) == 0) { ws1[t >> 6] = s1; ws2[t >> 6] = s2; }
    __syncthreads();
    s1 = ws1[0] + ws1[1] + ws1[2] + ws1[3];
    s2 = ws2[0] + ws2[1] + ws2[2] + ws2[3];
    const float mean = s1 * (1.f / 1024.f);
    const float var = s2 * (1.f / 1024.f) - mean * mean;
    const float rstd = rsqrtf(var + 1e-5f);
    float4 gg = reinterpret_cast<const float4*>(g)[t];
    float4 bb = reinterpret_cast<const float4*>(be)[t];
    float o0 = (v0 - mean) * rstd * gg.x + bb.x;
    float o1 = (v1 - mean) * rstd * gg.y + bb.y;
    float o2 = (v2 - mean) * rstd * gg.z + bb.z;
    float o3 = (v3 - mean) * rstd * gg.w + bb.w;
    float4 out = { o0, o1, o2, o3 };
    reinterpret_cast<float4*>(y + (size_t)row * 1024)[t] = out;
    if (yb) {
        ushort4 ob = { f2b(o0), f2b(o1), f2b(o2), f2b(o3) };
        reinterpret_cast<ushort4*>(yb + (size_t)row * 1024)[t] = ob;
    }
}

// ---------------------------------------------------------------------------
extern "C" void kernel_launch(void* const* d_in, const int* in_sizes, int n_in,
                              void* d_out, int out_size, void* d_ws, size_t ws_size,
                              hipStream_t stream) {
    const float* x_in = (const float*)d_in[0];
    const float* Wqkv = (const float*)d_in[1];
    const float* bqkv = (const float*)d_in[2];
    const float* W1   = (const float*)d_in[3];
    const float* b1   = (const float*)d_in[4];
    const float* W2   = (const float*)d_in[5];
    const float* b2   = (const float*)d_in[6];
    const float* g1   = (const float*)d_in[7];
    const float* be1  = (const float*)d_in[8];
    const float* g2   = (const float*)d_in[9];
    const float* be2  = (const float*)d_in[10];

    const int Bv = 2, N = 2048, L = 4, Hh = 16;
    const int R = Bv * N;  // 4096 token rows

    char* p = (char*)d_ws;
    auto alloc = [&](size_t bytes) { char* r = p; p += (bytes + 255) & ~(size_t)255; return r; };
    bf16*  Wqkvt = (bf16*)alloc((size_t)L * 3072 * 1024 * 2);
    bf16*  W1t   = (bf16*)alloc((size_t)L * 4096 * 1024 * 2);
    bf16*  W2t   = (bf16*)alloc((size_t)L * 1024 * 4096 * 2);
    bf16*  xb    = (bf16*)alloc((size_t)R * 1024 * 2);
    bf16*  qkvb  = (bf16*)alloc((size_t)R * 3072 * 2);
    float* obuf  = (float*)alloc((size_t)R * 1024 * 4);
    float* hbuf  = (float*)alloc((size_t)R * 1024 * 4);
    bf16*  hb    = (bf16*)alloc((size_t)R * 1024 * 2);
    bf16*  f1b   = (bf16*)alloc((size_t)R * 4096 * 2);
    float* xcur  = (float*)alloc((size_t)R * 1024 * 4);
    float* f2buf = obuf;        // obuf dead after LN1 -> reuse for f2
    bf16*  vtg   = (bf16*)hbuf; // 8.4MB V^T; hbuf region dead during qkv-gemm/attn

    transpose_cast<<<dim3(3072 / 32, 1024 / 32, L), dim3(32, 8), 0, stream>>>(Wqkv, Wqkvt, 1024, 3072);
    transpose_cast<<<dim3(4096 / 32, 1024 / 32, L), dim3(32, 8), 0, stream>>>(W1, W1t, 1024, 4096);
    transpose_cast<<<dim3(1024 / 32, 4096 / 32, L), dim3(32, 8), 0, stream>>>(W2, W2t, 4096, 1024);
    cast_bf16_k<<<(R * 1024 / 4 + 255) / 256, 256, 0, stream>>>(x_in, xb, R * 1024 / 4);

    const float* xres = x_in;
    for (int l = 0; l < L; ++l) {
        // qkv = x @ Wqkv + bqkv  -> bf16
        gemm_bf16<0><<<(3072 / 128) * (R / 128), 256, 0, stream>>>(
            xb, Wqkvt + (size_t)l * 3072 * 1024, bqkv + l * 3072, qkvb, R, 3072, 1024, 3072 / 128);
        // V^T per (b,h): [dh][N]
        vtrans<<<dim3(N / 32, 2, Bv * Hh), dim3(32, 8), 0, stream>>>(qkvb, vtg, N);
        // o = softmax(q k^T / 32) v
        attn_fwd<<<(N / 64) * (Bv * Hh), 256, 0, stream>>>(qkvb, vtg, obuf, N);
        // h = LN(o + x)   (overwrites vtg region -- attn already done)
        ln_res<<<R, 256, 0, stream>>>(obuf, xres, g1 + l * 1024, be1 + l * 1024, hbuf, hb);
        // f1 = gelu(h @ W1 + b1) -> bf16
        gemm_bf16<1><<<(4096 / 128) * (R / 128), 256, 0, stream>>>(
            hb, W1t + (size_t)l * 4096 * 1024, b1 + l * 4096, f1b, R, 4096, 1024, 4096 / 128);
        // f2 = gelu(f1 @ W2 + b2) -> fp32
        gemm_bf16<2><<<(1024 / 128) * (R / 128), 256, 0, stream>>>(
            f1b, W2t + (size_t)l * 1024 * 4096, b2 + l * 1024, f2buf, R, 1024, 4096, 1024 / 128);
        // x = LN(f2 + h), also emit bf16 copy for next layer's GEMM
        float* xn = (l == L - 1) ? (float*)d_out : xcur;
        ln_res<<<R, 256, 0, stream>>>(f2buf, hbuf, g2 + l * 1024, be2 + l * 1024, xn, xb);
        xres = xn;
    }
}

// Round 8
// 1245.679 us; speedup vs baseline: 1.0078x; 1.0049x over previous
//
#include <hip/hip_runtime.h>
#include <hip/hip_bf16.h>
#include <cmath>

// ---------------------------------------------------------------------------
// TextEncoder: 4-layer post-LN transformer, B=2 N=2048 D=1024 H=16 dh=64 FF=4096
// R4: (1) GEMM epilogue: erff -> fast tanh-gelu (exp2+rcp, ~10 ops, |err|<1e-3).
//     (2) attn: P^T relayout via per-wave LDS (4x ds_write_b64 + 2x ds_read_b128
//         replaces 16 shfl + 8 select); defer-max (T13, thr=11 in exp2 domain)
//         skips O-rescale + cross-lane max on most kv-tiles.
// ---------------------------------------------------------------------------

typedef __attribute__((ext_vector_type(8))) short bf16x8;
typedef __attribute__((ext_vector_type(4))) float f32x4;
typedef __hip_bfloat16 bf16;

#define DEV static __device__ __forceinline__

DEV unsigned short f2b(float f) {
    bf16 h = __float2bfloat16(f);
    return *reinterpret_cast<unsigned short*>(&h);
}

DEV unsigned int pack_bf16(float lo, float hi) {
    return (unsigned int)f2b(lo) | ((unsigned int)f2b(hi) << 16);
}

// tanh-form gelu: max abs deviation from exact ~1e-3, ~10 VALU ops.
DEV float gelu_fast(float x) {
    float u = 0.7978845608028654f * fmaf(0.044715f * x, x * x, x);
    u = fminf(fmaxf(u, -15.f), 15.f);               // v_med3; keeps exp2 finite
    float t = __builtin_amdgcn_exp2f(u * 2.8853900817779268f);  // e^(2u)
    float th = (t - 1.0f) * __builtin_amdgcn_rcpf(t + 1.0f);    // tanh(u)
    return 0.5f * x * (1.0f + th);
}

DEV void gload_lds16(const bf16* g, bf16* l) {
    __builtin_amdgcn_global_load_lds(
        (const __attribute__((address_space(1))) void*)g,
        (__attribute__((address_space(3))) void*)l, 16, 0, 0);
}

// ---- weight transpose + cast: Wt[l][n][k] = (bf16) W[l][k][n] --------------
__global__ __launch_bounds__(256) void transpose_cast(const float* __restrict__ W,
                                                      bf16* __restrict__ Wt,
                                                      int K, int Nm) {
    __shared__ float tile[32][33];
    const int l = blockIdx.z;
    const float* Wl = W + (size_t)l * K * Nm;
    bf16* Wtl = Wt + (size_t)l * K * Nm;
    const int n0 = blockIdx.x * 32, k0 = blockIdx.y * 32;
    const int tx = threadIdx.x, ty = threadIdx.y;
#pragma unroll
    for (int i = 0; i < 4; ++i)
        tile[ty + 8 * i][tx] = Wl[(size_t)(k0 + ty + 8 * i) * Nm + n0 + tx];
    __syncthreads();
#pragma unroll
    for (int i = 0; i < 4; ++i)
        Wtl[(size_t)(n0 + ty + 8 * i) * K + k0 + tx] = __float2bfloat16(tile[tx][ty + 8 * i]);
}

// ---- V transpose: qkv[b,n,2048+h*64+d] -> vtg[(b*16+h)*64+d][n]  (bf16) ----
__global__ __launch_bounds__(256) void vtrans(const bf16* __restrict__ qkv,
                                              bf16* __restrict__ vtg, int N) {
    __shared__ bf16 tile[32][33];
    const int bh = blockIdx.z, b = bh >> 4, h = bh & 15;
    const int n0 = blockIdx.x * 32, d0 = blockIdx.y * 32;
    const int tx = threadIdx.x, ty = threadIdx.y;
    const bf16* src = qkv + (size_t)(b * N + n0) * 3072 + 2048 + h * 64 + d0;
#pragma unroll
    for (int i = 0; i < 4; ++i)
        tile[ty + 8 * i][tx] = src[(size_t)(ty + 8 * i) * 3072 + tx];
    __syncthreads();
    bf16* dst = vtg + ((size_t)bh * 64 + d0) * N + n0;
#pragma unroll
    for (int i = 0; i < 4; ++i)
        dst[(size_t)(ty + 8 * i) * N + tx] = tile[tx][ty + 8 * i];
}

// ---- elementwise fp32 -> bf16 ----------------------------------------------
__global__ __launch_bounds__(256) void cast_bf16_k(const float* __restrict__ in,
                                                   bf16* __restrict__ out, int n4) {
    int i = blockIdx.x * 256 + threadIdx.x;
    if (i >= n4) return;
    float4 v = reinterpret_cast<const float4*>(in)[i];
    ushort4 o = { f2b(v.x), f2b(v.y), f2b(v.z), f2b(v.w) };
    reinterpret_cast<ushort4*>(out)[i] = o;
}

// ---- bf16 MFMA GEMM (m97 pattern): C[M,Nm] = A[M,K] @ Bt[Nm,K]^T + bias ----
// 1D grid with XCD-chunked swizzle (nwg % 8 == 0 for all our shapes).
template <int EPI>
__global__ __launch_bounds__(256) void gemm_bf16(const bf16* __restrict__ A,
                                                 const bf16* __restrict__ Bt,
                                                 const float* __restrict__ bias,
                                                 void* __restrict__ Cout,
                                                 int M, int Nm, int K, int nbx) {
    __shared__ bf16 As[128][64];  // linear: required by global_load_lds
    __shared__ bf16 Bs[128][64];
    const int nwg = gridDim.x;
    int id = blockIdx.x;
    if ((nwg & 7) == 0) id = (id & 7) * (nwg >> 3) + (id >> 3);  // XCD-chunked
    const int m0 = (id / nbx) * 128, n0 = (id % nbx) * 128;
    const int t = threadIdx.x, w = t >> 6, lane = t & 63;
    const int wr = (w >> 1) * 64, wc = (w & 1) * 64;
    const int lr = lane & 15, lg = lane >> 4;
    const int srowbase = w * 32;
    const int slrow = lane >> 3;
    const int scol = (lane & 7) * 8;

    f32x4 acc[4][4] = {};

    for (int k0 = 0; k0 < K; k0 += 64) {
        __syncthreads();
#pragma unroll
        for (int p = 0; p < 4; ++p) {
            const int r = srowbase + p * 8;
            gload_lds16(A + (size_t)(m0 + r + slrow) * K + k0 + scol, &As[r][0]);
            gload_lds16(Bt + (size_t)(n0 + r + slrow) * K + k0 + scol, &Bs[r][0]);
        }
        __syncthreads();
#pragma unroll
        for (int kk = 0; kk < 2; ++kk) {
            const int lk = kk * 32 + lg * 8;
            bf16x8 a[4], b[4];
#pragma unroll
            for (int m = 0; m < 4; ++m)
                a[m] = *reinterpret_cast<const bf16x8*>(&As[wr + m * 16 + lr][lk]);
#pragma unroll
            for (int n = 0; n < 4; ++n)
                b[n] = *reinterpret_cast<const bf16x8*>(&Bs[wc + n * 16 + lr][lk]);
#pragma unroll
            for (int m = 0; m < 4; ++m)
#pragma unroll
                for (int n = 0; n < 4; ++n)
                    acc[m][n] = __builtin_amdgcn_mfma_f32_16x16x32_bf16(a[m], b[n], acc[m][n], 0, 0, 0);
        }
    }

#pragma unroll
    for (int n = 0; n < 4; ++n) {
        const int col = n0 + wc + n * 16 + lr;
        const float bc = bias[col];
#pragma unroll
        for (int m = 0; m < 4; ++m) {
            const int row = m0 + wr + m * 16 + lg * 4;
#pragma unroll
            for (int j = 0; j < 4; ++j) {
                float v = acc[m][n][j] + bc;
                if (EPI >= 1) v = gelu_fast(v);
                if (EPI == 2)
                    reinterpret_cast<float*>(Cout)[(size_t)(row + j) * Nm + col] = v;
                else
                    reinterpret_cast<bf16*>(Cout)[(size_t)(row + j) * Nm + col] = __float2bfloat16(v);
            }
        }
    }
}

// ---- flash attention, swapped-operand form ---------------------------------
// grid 1D (N/64)*(B*H) swizzled; block 256 (4 waves); each wave owns 16 q-rows.
// S^T = mfma(K, Q): lane holds q=lr, kv=16c+4lg+j -> lane-local softmax.
// PV: O^T = mfma(V^T, P^T); P^T routed through per-wave LDS tile Ps[q][kv].
__global__ __launch_bounds__(256) void attn_fwd(const bf16* __restrict__ qkv,
                                                const bf16* __restrict__ vtg,
                                                float* __restrict__ o, int N) {
    __shared__ bf16 Ks[64][72];      // K tile [kv][dh], padded
    __shared__ bf16 Vs[64][72];      // V^T tile [dh][kv], padded
    __shared__ bf16 Ps[4][16][72];   // per-wave P [q][kv], padded
    const int nwg = gridDim.x, nbx = N / 64;
    int id = blockIdx.x;
    id = (id & 7) * (nwg >> 3) + (id >> 3);  // XCD-chunked: 4 heads' K/V per L2
    const int bh = id / nbx, b = bh >> 4, h = bh & 15;
    const int q0 = (id % nbx) * 64;
    const int t = threadIdx.x, w = t >> 6, lane = t & 63;
    const int lr = lane & 15, lg = lane >> 4;
    const bf16* base = qkv + (size_t)b * N * 3072;
    const bf16* vbase = vtg + (size_t)bh * 64 * N;

    // Q as B-operand: col q = lr, k = 32f + 8lg + i
    bf16x8 qf[2];
    {
        const bf16* qp = base + (size_t)(q0 + w * 16 + lr) * 3072 + h * 64 + lg * 8;
        qf[0] = *reinterpret_cast<const bf16x8*>(qp);
        qf[1] = *reinterpret_cast<const bf16x8*>(qp + 32);
    }

    float mrow = -INFINITY, lrow = 0.f;
    f32x4 oacc[4] = {};
    const float scale2 = 0.03125f * 1.44269504088896340736f;  // embedDim^-0.5 * log2(e)
    const int srow = t >> 2, scol = (t & 3) * 8;

    for (int kv0 = 0; kv0 < N; kv0 += 64) {
        __syncthreads();
        {   // stage K [kv][dh] and V^T [dh][kv]
            const bf16* ksrc = base + (size_t)(kv0 + srow) * 3072 + 1024 + h * 64 + scol;
            *reinterpret_cast<uint4*>(&Ks[srow][scol])      = *reinterpret_cast<const uint4*>(ksrc);
            *reinterpret_cast<uint4*>(&Ks[srow][scol + 32]) = *reinterpret_cast<const uint4*>(ksrc + 32);
            const bf16* vsrc = vbase + (size_t)srow * N + kv0 + scol;
            *reinterpret_cast<uint4*>(&Vs[srow][scol])      = *reinterpret_cast<const uint4*>(vsrc);
            *reinterpret_cast<uint4*>(&Vs[srow][scol + 32]) = *reinterpret_cast<const uint4*>(vsrc + 32);
        }
        __syncthreads();

        // S^T[kv][q] = K @ Q^T : A = K-frag (rows kv), B = Q-frag (cols q)
        f32x4 st[4] = {};
#pragma unroll
        for (int f = 0; f < 2; ++f)
#pragma unroll
            for (int c = 0; c < 4; ++c) {
                bf16x8 ka = *reinterpret_cast<const bf16x8*>(&Ks[c * 16 + lr][f * 32 + lg * 8]);
                st[c] = __builtin_amdgcn_mfma_f32_16x16x32_bf16(ka, qf[f], st[c], 0, 0, 0);
            }

        // lane-local max over this lane's 16 kv values (exp2 domain)
        float smax = st[0][0];
#pragma unroll
        for (int c = 0; c < 4; ++c)
#pragma unroll
            for (int j = 0; j < 4; ++j) smax = fmaxf(smax, st[c][j]);
        const float tilemax = smax * scale2;

        // defer-max (T13): rescale only when some lane exceeds mrow by >11
        // (P bounded by 2^11 = 2048 -- fine in bf16/fp32 accumulation)
        if (!__all(tilemax - mrow <= 11.0f)) {
            float tm = fmaxf(tilemax, __shfl_xor(tilemax, 16, 64));
            tm = fmaxf(tm, __shfl_xor(tm, 32, 64));   // uniform across lg for fixed q
            const float mnew = fmaxf(mrow, tm);
            const float al = __builtin_amdgcn_exp2f(mrow - mnew);
            mrow = mnew;
            lrow *= al;
#pragma unroll
            for (int c = 0; c < 4; ++c)
#pragma unroll
                for (int j = 0; j < 4; ++j) oacc[c][j] *= al;
        }

        float p[4][4];
        float psum = 0.f;
#pragma unroll
        for (int c = 0; c < 4; ++c)
#pragma unroll
            for (int j = 0; j < 4; ++j) {
                p[c][j] = __builtin_amdgcn_exp2f(fmaf(st[c][j], scale2, -mrow));
                psum += p[c][j];
            }
        psum += __shfl_xor(psum, 16, 64);
        psum += __shfl_xor(psum, 32, 64);
        lrow += psum;

        // write P to per-wave LDS: lane holds P[q=lr][kv=16c+4lg+{0..3}]
#pragma unroll
        for (int c = 0; c < 4; ++c) {
            uint2 pr = { pack_bf16(p[c][0], p[c][1]), pack_bf16(p[c][2], p[c][3]) };
            *reinterpret_cast<uint2*>(&Ps[w][lr][c * 16 + lg * 4]) = pr;
        }
        asm volatile("s_waitcnt lgkmcnt(0)" ::: "memory");  // in-wave write->read
        __builtin_amdgcn_sched_barrier(0);

        // O^T += V^T @ P^T : B-frag col q=lr, k = f*32+lg*8+i -> Ps[lr][...]
#pragma unroll
        for (int f = 0; f < 2; ++f) {
            bf16x8 pb = *reinterpret_cast<const bf16x8*>(&Ps[w][lr][f * 32 + lg * 8]);
#pragma unroll
            for (int c = 0; c < 4; ++c) {
                bf16x8 va = *reinterpret_cast<const bf16x8*>(&Vs[c * 16 + lr][f * 32 + lg * 8]);
                oacc[c] = __builtin_amdgcn_mfma_f32_16x16x32_bf16(va, pb, oacc[c], 0, 0, 0);
            }
        }
    }

    // O^T layout: col q = lr, row d = 16c + 4lg + j -> float4 stores
    const float linv = 1.f / lrow;
    float* op = o + ((size_t)b * N + q0 + w * 16 + lr) * 1024 + h * 64;
#pragma unroll
    for (int c = 0; c < 4; ++c) {
        float4 v = { oacc[c][0] * linv, oacc[c][1] * linv,
                     oacc[c][2] * linv, oacc[c][3] * linv };
        *reinterpret_cast<float4*>(op + c * 16 + lg * 4) = v;
    }
}

// ---- fused residual + LayerNorm (fp32), optional bf16 copy -----------------
__global__ __launch_bounds__(256) void ln_res(const float* __restrict__ a,
                                              const float* __restrict__ r,
                                              const float* __restrict__ g,
                                              const float* __restrict__ be,
                                              float* __restrict__ y,
                                              bf16* __restrict__ yb) {
    const int row = blockIdx.x, t = threadIdx.x;
    float4 va = reinterpret_cast<const float4*>(a + (size_t)row * 1024)[t];
    float4 vr = reinterpret_cast<const float4*>(r + (size_t)row * 1024)[t];
    float v0 = va.x + vr.x, v1 = va.y + vr.y, v2 = va.z + vr.z, v3 = va.w + vr.w;
    float s1 = v0 + v1 + v2 + v3;
    float s2 = v0 * v0 + v1 * v1 + v2 * v2 + v3 * v3;
#pragma unroll
    for (int m = 1; m < 64; m <<= 1) {
        s1 += __shfl_xor(s1, m, 64);
        s2 += __shfl_xor(s2, m, 64);
    }
    __shared__ float ws1[4], ws2[4];
    if ((t & 63) == 0) { ws1[t >> 6] = s1; ws2[t >> 6] = s2; }
    __syncthreads();
    s1 = ws1[0] + ws1[1] + ws1[2] + ws1[3];
    s2 = ws2[0] + ws2[1] + ws2[2] + ws2[3];
    const float mean = s1 * (1.f / 1024.f);
    const float var = s2 * (1.f / 1024.f) - mean * mean;
    const float rstd = rsqrtf(var + 1e-5f);
    float4 gg = reinterpret_cast<const float4*>(g)[t];
    float4 bb = reinterpret_cast<const float4*>(be)[t];
    float o0 = (v0 - mean) * rstd * gg.x + bb.x;
    float o1 = (v1 - mean) * rstd * gg.y + bb.y;
    float o2 = (v2 - mean) * rstd * gg.z + bb.z;
    float o3 = (v3 - mean) * rstd * gg.w + bb.w;
    float4 out = { o0, o1, o2, o3 };
    reinterpret_cast<float4*>(y + (size_t)row * 1024)[t] = out;
    if (yb) {
        ushort4 ob = { f2b(o0), f2b(o1), f2b(o2), f2b(o3) };
        reinterpret_cast<ushort4*>(yb + (size_t)row * 1024)[t] = ob;
    }
}

// ---------------------------------------------------------------------------
extern "C" void kernel_launch(void* const* d_in, const int* in_sizes, int n_in,
                              void* d_out, int out_size, void* d_ws, size_t ws_size,
                              hipStream_t stream) {
    const float* x_in = (const float*)d_in[0];
    const float* Wqkv = (const float*)d_in[1];
    const float* bqkv = (const float*)d_in[2];
    const float* W1   = (const float*)d_in[3];
    const float* b1   = (const float*)d_in[4];
    const float* W2   = (const float*)d_in[5];
    const float* b2   = (const float*)d_in[6];
    const float* g1   = (const float*)d_in[7];
    const float* be1  = (const float*)d_in[8];
    const float* g2   = (const float*)d_in[9];
    const float* be2  = (const float*)d_in[10];

    const int Bv = 2, N = 2048, L = 4, Hh = 16;
    const int R = Bv * N;  // 4096 token rows

    char* p = (char*)d_ws;
    auto alloc = [&](size_t bytes) { char* r = p; p += (bytes + 255) & ~(size_t)255; return r; };
    bf16*  Wqkvt = (bf16*)alloc((size_t)L * 3072 * 1024 * 2);
    bf16*  W1t   = (bf16*)alloc((size_t)L * 4096 * 1024 * 2);
    bf16*  W2t   = (bf16*)alloc((size_t)L * 1024 * 4096 * 2);
    bf16*  xb    = (bf16*)alloc((size_t)R * 1024 * 2);
    bf16*  qkvb  = (bf16*)alloc((size_t)R * 3072 * 2);
    float* obuf  = (float*)alloc((size_t)R * 1024 * 4);
    float* hbuf  = (float*)alloc((size_t)R * 1024 * 4);
    bf16*  hb    = (bf16*)alloc((size_t)R * 1024 * 2);
    bf16*  f1b   = (bf16*)alloc((size_t)R * 4096 * 2);
    float* xcur  = (float*)alloc((size_t)R * 1024 * 4);
    float* f2buf = obuf;        // obuf dead after LN1 -> reuse for f2
    bf16*  vtg   = (bf16*)hbuf; // 8.4MB V^T; hbuf region dead during qkv-gemm/attn

    transpose_cast<<<dim3(3072 / 32, 1024 / 32, L), dim3(32, 8), 0, stream>>>(Wqkv, Wqkvt, 1024, 3072);
    transpose_cast<<<dim3(4096 / 32, 1024 / 32, L), dim3(32, 8), 0, stream>>>(W1, W1t, 1024, 4096);
    transpose_cast<<<dim3(1024 / 32, 4096 / 32, L), dim3(32, 8), 0, stream>>>(W2, W2t, 4096, 1024);
    cast_bf16_k<<<(R * 1024 / 4 + 255) / 256, 256, 0, stream>>>(x_in, xb, R * 1024 / 4);

    const float* xres = x_in;
    for (int l = 0; l < L; ++l) {
        // qkv = x @ Wqkv + bqkv  -> bf16
        gemm_bf16<0><<<(3072 / 128) * (R / 128), 256, 0, stream>>>(
            xb, Wqkvt + (size_t)l * 3072 * 1024, bqkv + l * 3072, qkvb, R, 3072, 1024, 3072 / 128);
        // V^T per (b,h): [dh][N]
        vtrans<<<dim3(N / 32, 2, Bv * Hh), dim3(32, 8), 0, stream>>>(qkvb, vtg, N);
        // o = softmax(q k^T / 32) v
        attn_fwd<<<(N / 64) * (Bv * Hh), 256, 0, stream>>>(qkvb, vtg, obuf, N);
        // h = LN(o + x)   (overwrites vtg region -- attn already done)
        ln_res<<<R, 256, 0, stream>>>(obuf, xres, g1 + l * 1024, be1 + l * 1024, hbuf, hb);
        // f1 = gelu(h @ W1 + b1) -> bf16
        gemm_bf16<1><<<(4096 / 128) * (R / 128), 256, 0, stream>>>(
            hb, W1t + (size_t)l * 4096 * 1024, b1 + l * 4096, f1b, R, 4096, 1024, 4096 / 128);
        // f2 = gelu(f1 @ W2 + b2) -> fp32
        gemm_bf16<2><<<(1024 / 128) * (R / 128), 256, 0, stream>>>(
            f1b, W2t + (size_t)l * 1024 * 4096, b2 + l * 1024, f2buf, R, 1024, 4096, 1024 / 128);
        // x = LN(f2 + h), also emit bf16 copy for next layer's GEMM
        float* xn = (l == L - 1) ? (float*)d_out : xcur;
        ln_res<<<R, 256, 0, stream>>>(f2buf, hbuf, g2 + l * 1024, be2 + l * 1024, xn, xb);
        xres = xn;
    }
}

// Round 10
// 1132.287 us; speedup vs baseline: 1.1088x; 1.1001x over previous
//
#include <hip/hip_runtime.h>
#include <hip/hip_bf16.h>
#include <cmath>

// ---------------------------------------------------------------------------
// TextEncoder: 4-layer post-LN transformer, B=2 N=2048 D=1024 H=16 dh=64 FF=4096
// R9: R8 structure (256x256 pipelined gemm256 for f1/f2, f2 split-K=4) with the
// workspace-overflow fixed: split-K partials are bf16 and alias the dead
// xb+qkvb region (no net new workspace vs the passing R4 layout).
// ---------------------------------------------------------------------------

typedef __attribute__((ext_vector_type(8))) short bf16x8;
typedef __attribute__((ext_vector_type(4))) float f32x4;
typedef __hip_bfloat16 bf16;

#define DEV static __device__ __forceinline__

DEV unsigned short f2b(float f) {
    bf16 h = __float2bfloat16(f);
    return *reinterpret_cast<unsigned short*>(&h);
}

DEV unsigned int pack_bf16(float lo, float hi) {
    return (unsigned int)f2b(lo) | ((unsigned int)f2b(hi) << 16);
}

DEV float b2f(unsigned short u) {
    unsigned int x = ((unsigned int)u) << 16;
    return *reinterpret_cast<float*>(&x);
}

// tanh-form gelu: max abs deviation from exact ~1e-3, ~10 VALU ops.
DEV float gelu_fast(float x) {
    float u = 0.7978845608028654f * fmaf(0.044715f * x, x * x, x);
    u = fminf(fmaxf(u, -15.f), 15.f);               // v_med3; keeps exp2 finite
    float t = __builtin_amdgcn_exp2f(u * 2.8853900817779268f);  // e^(2u)
    float th = (t - 1.0f) * __builtin_amdgcn_rcpf(t + 1.0f);    // tanh(u)
    return 0.5f * x * (1.0f + th);
}

DEV void gload_lds16(const bf16* g, bf16* l) {
    __builtin_amdgcn_global_load_lds(
        (const __attribute__((address_space(1))) void*)g,
        (__attribute__((address_space(3))) void*)l, 16, 0, 0);
}

// ---- weight transpose + cast: Wt[l][n][k] = (bf16) W[l][k][n] --------------
__global__ __launch_bounds__(256) void transpose_cast(const float* __restrict__ W,
                                                      bf16* __restrict__ Wt,
                                                      int K, int Nm) {
    __shared__ float tile[32][33];
    const int l = blockIdx.z;
    const float* Wl = W + (size_t)l * K * Nm;
    bf16* Wtl = Wt + (size_t)l * K * Nm;
    const int n0 = blockIdx.x * 32, k0 = blockIdx.y * 32;
    const int tx = threadIdx.x, ty = threadIdx.y;
#pragma unroll
    for (int i = 0; i < 4; ++i)
        tile[ty + 8 * i][tx] = Wl[(size_t)(k0 + ty + 8 * i) * Nm + n0 + tx];
    __syncthreads();
#pragma unroll
    for (int i = 0; i < 4; ++i)
        Wtl[(size_t)(n0 + ty + 8 * i) * K + k0 + tx] = __float2bfloat16(tile[tx][ty + 8 * i]);
}

// ---- V transpose: qkv[b,n,2048+h*64+d] -> vtg[(b*16+h)*64+d][n]  (bf16) ----
__global__ __launch_bounds__(256) void vtrans(const bf16* __restrict__ qkv,
                                              bf16* __restrict__ vtg, int N) {
    __shared__ bf16 tile[32][33];
    const int bh = blockIdx.z, b = bh >> 4, h = bh & 15;
    const int n0 = blockIdx.x * 32, d0 = blockIdx.y * 32;
    const int tx = threadIdx.x, ty = threadIdx.y;
    const bf16* src = qkv + (size_t)(b * N + n0) * 3072 + 2048 + h * 64 + d0;
#pragma unroll
    for (int i = 0; i < 4; ++i)
        tile[ty + 8 * i][tx] = src[(size_t)(ty + 8 * i) * 3072 + tx];
    __syncthreads();
    bf16* dst = vtg + ((size_t)bh * 64 + d0) * N + n0;
#pragma unroll
    for (int i = 0; i < 4; ++i)
        dst[(size_t)(ty + 8 * i) * N + tx] = tile[tx][ty + 8 * i];
}

// ---- elementwise fp32 -> bf16 ----------------------------------------------
__global__ __launch_bounds__(256) void cast_bf16_k(const float* __restrict__ in,
                                                   bf16* __restrict__ out, int n4) {
    int i = blockIdx.x * 256 + threadIdx.x;
    if (i >= n4) return;
    float4 v = reinterpret_cast<const float4*>(in)[i];
    ushort4 o = { f2b(v.x), f2b(v.y), f2b(v.z), f2b(v.w) };
    reinterpret_cast<ushort4*>(out)[i] = o;
}

// ---- bf16 MFMA GEMM 128x128 (m97 pattern, serialized) -- used for qkv ------
template <int EPI>
__global__ __launch_bounds__(256) void gemm_bf16(const bf16* __restrict__ A,
                                                 const bf16* __restrict__ Bt,
                                                 const float* __restrict__ bias,
                                                 void* __restrict__ Cout,
                                                 int M, int Nm, int K, int nbx) {
    __shared__ bf16 As[128][64];  // linear: required by global_load_lds
    __shared__ bf16 Bs[128][64];
    const int nwg = gridDim.x;
    int id = blockIdx.x;
    if ((nwg & 7) == 0) id = (id & 7) * (nwg >> 3) + (id >> 3);  // XCD-chunked
    const int m0 = (id / nbx) * 128, n0 = (id % nbx) * 128;
    const int t = threadIdx.x, w = t >> 6, lane = t & 63;
    const int wr = (w >> 1) * 64, wc = (w & 1) * 64;
    const int lr = lane & 15, lg = lane >> 4;
    const int srowbase = w * 32;
    const int slrow = lane >> 3;
    const int scol = (lane & 7) * 8;

    f32x4 acc[4][4] = {};

    for (int k0 = 0; k0 < K; k0 += 64) {
        __syncthreads();
#pragma unroll
        for (int p = 0; p < 4; ++p) {
            const int r = srowbase + p * 8;
            gload_lds16(A + (size_t)(m0 + r + slrow) * K + k0 + scol, &As[r][0]);
            gload_lds16(Bt + (size_t)(n0 + r + slrow) * K + k0 + scol, &Bs[r][0]);
        }
        __syncthreads();
#pragma unroll
        for (int kk = 0; kk < 2; ++kk) {
            const int lk = kk * 32 + lg * 8;
            bf16x8 a[4], b[4];
#pragma unroll
            for (int m = 0; m < 4; ++m)
                a[m] = *reinterpret_cast<const bf16x8*>(&As[wr + m * 16 + lr][lk]);
#pragma unroll
            for (int n = 0; n < 4; ++n)
                b[n] = *reinterpret_cast<const bf16x8*>(&Bs[wc + n * 16 + lr][lk]);
#pragma unroll
            for (int m = 0; m < 4; ++m)
#pragma unroll
                for (int n = 0; n < 4; ++n)
                    acc[m][n] = __builtin_amdgcn_mfma_f32_16x16x32_bf16(a[m], b[n], acc[m][n], 0, 0, 0);
        }
    }

#pragma unroll
    for (int n = 0; n < 4; ++n) {
        const int col = n0 + wc + n * 16 + lr;
        const float bc = bias[col];
#pragma unroll
        for (int m = 0; m < 4; ++m) {
            const int row = m0 + wr + m * 16 + lg * 4;
#pragma unroll
            for (int j = 0; j < 4; ++j) {
                float v = acc[m][n][j] + bc;
                if (EPI >= 1) v = gelu_fast(v);
                reinterpret_cast<bf16*>(Cout)[(size_t)(row + j) * Nm + col] = __float2bfloat16(v);
            }
        }
    }
}

// ---- 256x256 pipelined GEMM (counted vmcnt + raw barriers), 8 waves --------
// EPI: 1 = bias+gelu -> bf16 out; 3 = raw bf16 partial (split-K), no bias.
// Grid 1D = ntiles * nsplit, XCD-chunked (grid % 8 == 0).
// K = per-split depth; Ktotal = full row stride of A / Bt.
template <int EPI>
__global__ __launch_bounds__(512, 2) void gemm256(const bf16* __restrict__ A,
                                                  const bf16* __restrict__ Bt,
                                                  const float* __restrict__ bias,
                                                  void* __restrict__ Cout,
                                                  int M, int Nm, int K,
                                                  int nbx, int ntiles, int Ktotal) {
    __shared__ bf16 As[2][256][64];   // 64 KB
    __shared__ bf16 Bs[2][256][64];   // 64 KB
    const int nwg = gridDim.x;
    int id = blockIdx.x;
    id = (id & 7) * (nwg >> 3) + (id >> 3);          // bijective: nwg % 8 == 0
    const int tile = id % ntiles, split = id / ntiles;
    const int m0 = (tile / nbx) * 256, n0 = (tile % nbx) * 256;
    const int kbase = split * K;
    const int t = threadIdx.x, w = t >> 6, lane = t & 63;
    const int wm = w >> 2, wn = w & 3;               // 2 x 4 wave grid
    const int lr = lane & 15, lg = lane >> 4;
    const int srow = w * 8;                          // wave-uniform staging row base
    const bf16* Ag = A + (size_t)(m0 + srow + (lane >> 3)) * Ktotal + kbase + (lane & 7) * 8;
    const bf16* Bg = Bt + (size_t)(n0 + srow + (lane >> 3)) * Ktotal + kbase + (lane & 7) * 8;

    f32x4 acc[8][4] = {};
    const int NT = K / 64;

    // stage K-tile kt (64 cols) into buffer b: 4 A passes + 4 B passes
#define STAGE256(kt, b)                                                          \
    {                                                                            \
        const size_t koff = (size_t)(kt) * 64;                                   \
        _Pragma("unroll")                                                        \
        for (int p = 0; p < 4; ++p)                                              \
            gload_lds16(Ag + (size_t)(p * 64) * Ktotal + koff,                   \
                        &As[b][p * 64 + srow][0]);                               \
        _Pragma("unroll")                                                        \
        for (int p = 0; p < 4; ++p)                                              \
            gload_lds16(Bg + (size_t)(p * 64) * Ktotal + koff,                   \
                        &Bs[b][p * 64 + srow][0]);                               \
    }

    STAGE256(0, 0);
    for (int kt = 0; kt < NT; ++kt) {
        const int buf = kt & 1;
        if (kt + 1 < NT) {
            STAGE256(kt + 1, buf ^ 1);
            asm volatile("s_waitcnt vmcnt(8)" ::: "memory");  // stage(kt) landed
        } else {
            asm volatile("s_waitcnt vmcnt(0)" ::: "memory");
        }
        __builtin_amdgcn_sched_barrier(0);
        __builtin_amdgcn_s_barrier();                          // all waves: tile kt ready
        __builtin_amdgcn_sched_barrier(0);
        __builtin_amdgcn_s_setprio(1);
#pragma unroll
        for (int kk = 0; kk < 2; ++kk) {
            const int lk = kk * 32 + lg * 8;
            bf16x8 a[8], b[4];
#pragma unroll
            for (int m = 0; m < 8; ++m)
                a[m] = *reinterpret_cast<const bf16x8*>(&As[buf][wm * 128 + m * 16 + lr][lk]);
#pragma unroll
            for (int n = 0; n < 4; ++n)
                b[n] = *reinterpret_cast<const bf16x8*>(&Bs[buf][wn * 64 + n * 16 + lr][lk]);
#pragma unroll
            for (int m = 0; m < 8; ++m)
#pragma unroll
                for (int n = 0; n < 4; ++n)
                    acc[m][n] = __builtin_amdgcn_mfma_f32_16x16x32_bf16(a[m], b[n], acc[m][n], 0, 0, 0);
        }
        __builtin_amdgcn_s_setprio(0);
        __builtin_amdgcn_sched_barrier(0);
        __builtin_amdgcn_s_barrier();                          // reads of buf done
        __builtin_amdgcn_sched_barrier(0);
    }
#undef STAGE256

    if (EPI == 3) {
        bf16* outp = (bf16*)Cout + (size_t)split * M * Nm;
#pragma unroll
        for (int n = 0; n < 4; ++n) {
            const int col = n0 + wn * 64 + n * 16 + lr;
#pragma unroll
            for (int m = 0; m < 8; ++m) {
                const int row = m0 + wm * 128 + m * 16 + lg * 4;
#pragma unroll
                for (int j = 0; j < 4; ++j)
                    outp[(size_t)(row + j) * Nm + col] = __float2bfloat16(acc[m][n][j]);
            }
        }
    } else {
#pragma unroll
        for (int n = 0; n < 4; ++n) {
            const int col = n0 + wn * 64 + n * 16 + lr;
            const float bc = bias[col];
#pragma unroll
            for (int m = 0; m < 8; ++m) {
                const int row = m0 + wm * 128 + m * 16 + lg * 4;
#pragma unroll
                for (int j = 0; j < 4; ++j) {
                    float v = gelu_fast(acc[m][n][j] + bc);
                    reinterpret_cast<bf16*>(Cout)[(size_t)(row + j) * Nm + col] = __float2bfloat16(v);
                }
            }
        }
    }
}

// ---- split-K reduce: out = gelu(p0+p1+p2+p3 + bias)  (bf16 partials) -------
// i indexes groups of 8 elements; Nm8 = columns/8; stride = M*Nm elements.
__global__ __launch_bounds__(256) void reduce4_gelu(const bf16* __restrict__ part,
                                                    const float* __restrict__ bias,
                                                    float* __restrict__ out,
                                                    int n8, int Nm8, size_t stride) {
    int i = blockIdx.x * 256 + threadIdx.x;
    if (i >= n8) return;
    const int cb = (i % Nm8) * 8;
    float s[8];
#pragma unroll
    for (int e = 0; e < 8; ++e) s[e] = bias[cb + e];
#pragma unroll
    for (int k = 0; k < 4; ++k) {
        bf16x8 v = *reinterpret_cast<const bf16x8*>(part + (size_t)k * stride + (size_t)i * 8);
#pragma unroll
        for (int e = 0; e < 8; ++e) s[e] += b2f((unsigned short)v[e]);
    }
    float4 r0 = { gelu_fast(s[0]), gelu_fast(s[1]), gelu_fast(s[2]), gelu_fast(s[3]) };
    float4 r1 = { gelu_fast(s[4]), gelu_fast(s[5]), gelu_fast(s[6]), gelu_fast(s[7]) };
    reinterpret_cast<float4*>(out)[2 * i]     = r0;
    reinterpret_cast<float4*>(out)[2 * i + 1] = r1;
}

// ---- flash attention, swapped-operand form (unchanged from R4) -------------
__global__ __launch_bounds__(256) void attn_fwd(const bf16* __restrict__ qkv,
                                                const bf16* __restrict__ vtg,
                                                float* __restrict__ o, int N) {
    __shared__ bf16 Ks[64][72];      // K tile [kv][dh], padded
    __shared__ bf16 Vs[64][72];      // V^T tile [dh][kv], padded
    __shared__ bf16 Ps[4][16][72];   // per-wave P [q][kv], padded
    const int nwg = gridDim.x, nbx = N / 64;
    int id = blockIdx.x;
    id = (id & 7) * (nwg >> 3) + (id >> 3);  // XCD-chunked: 4 heads' K/V per L2
    const int bh = id / nbx, b = bh >> 4, h = bh & 15;
    const int q0 = (id % nbx) * 64;
    const int t = threadIdx.x, w = t >> 6, lane = t & 63;
    const int lr = lane & 15, lg = lane >> 4;
    const bf16* base = qkv + (size_t)b * N * 3072;
    const bf16* vbase = vtg + (size_t)bh * 64 * N;

    bf16x8 qf[2];
    {
        const bf16* qp = base + (size_t)(q0 + w * 16 + lr) * 3072 + h * 64 + lg * 8;
        qf[0] = *reinterpret_cast<const bf16x8*>(qp);
        qf[1] = *reinterpret_cast<const bf16x8*>(qp + 32);
    }

    float mrow = -INFINITY, lrow = 0.f;
    f32x4 oacc[4] = {};
    const float scale2 = 0.03125f * 1.44269504088896340736f;  // embedDim^-0.5 * log2(e)
    const int srow = t >> 2, scol = (t & 3) * 8;

    for (int kv0 = 0; kv0 < N; kv0 += 64) {
        __syncthreads();
        {
            const bf16* ksrc = base + (size_t)(kv0 + srow) * 3072 + 1024 + h * 64 + scol;
            *reinterpret_cast<uint4*>(&Ks[srow][scol])      = *reinterpret_cast<const uint4*>(ksrc);
            *reinterpret_cast<uint4*>(&Ks[srow][scol + 32]) = *reinterpret_cast<const uint4*>(ksrc + 32);
            const bf16* vsrc = vbase + (size_t)srow * N + kv0 + scol;
            *reinterpret_cast<uint4*>(&Vs[srow][scol])      = *reinterpret_cast<const uint4*>(vsrc);
            *reinterpret_cast<uint4*>(&Vs[srow][scol + 32]) = *reinterpret_cast<const uint4*>(vsrc + 32);
        }
        __syncthreads();

        f32x4 st[4] = {};
#pragma unroll
        for (int f = 0; f < 2; ++f)
#pragma unroll
            for (int c = 0; c < 4; ++c) {
                bf16x8 ka = *reinterpret_cast<const bf16x8*>(&Ks[c * 16 + lr][f * 32 + lg * 8]);
                st[c] = __builtin_amdgcn_mfma_f32_16x16x32_bf16(ka, qf[f], st[c], 0, 0, 0);
            }

        float smax = st[0][0];
#pragma unroll
        for (int c = 0; c < 4; ++c)
#pragma unroll
            for (int j = 0; j < 4; ++j) smax = fmaxf(smax, st[c][j]);
        const float tilemax = smax * scale2;

        if (!__all(tilemax - mrow <= 11.0f)) {
            float tm = fmaxf(tilemax, __shfl_xor(tilemax, 16, 64));
            tm = fmaxf(tm, __shfl_xor(tm, 32, 64));
            const float mnew = fmaxf(mrow, tm);
            const float al = __builtin_amdgcn_exp2f(mrow - mnew);
            mrow = mnew;
            lrow *= al;
#pragma unroll
            for (int c = 0; c < 4; ++c)
#pragma unroll
                for (int j = 0; j < 4; ++j) oacc[c][j] *= al;
        }

        float p[4][4];
        float psum = 0.f;
#pragma unroll
        for (int c = 0; c < 4; ++c)
#pragma unroll
            for (int j = 0; j < 4; ++j) {
                p[c][j] = __builtin_amdgcn_exp2f(fmaf(st[c][j], scale2, -mrow));
                psum += p[c][j];
            }
        psum += __shfl_xor(psum, 16, 64);
        psum += __shfl_xor(psum, 32, 64);
        lrow += psum;

#pragma unroll
        for (int c = 0; c < 4; ++c) {
            uint2 pr = { pack_bf16(p[c][0], p[c][1]), pack_bf16(p[c][2], p[c][3]) };
            *reinterpret_cast<uint2*>(&Ps[w][lr][c * 16 + lg * 4]) = pr;
        }
        asm volatile("s_waitcnt lgkmcnt(0)" ::: "memory");
        __builtin_amdgcn_sched_barrier(0);

#pragma unroll
        for (int f = 0; f < 2; ++f) {
            bf16x8 pb = *reinterpret_cast<const bf16x8*>(&Ps[w][lr][f * 32 + lg * 8]);
#pragma unroll
            for (int c = 0; c < 4; ++c) {
                bf16x8 va = *reinterpret_cast<const bf16x8*>(&Vs[c * 16 + lr][f * 32 + lg * 8]);
                oacc[c] = __builtin_amdgcn_mfma_f32_16x16x32_bf16(va, pb, oacc[c], 0, 0, 0);
            }
        }
    }

    const float linv = 1.f / lrow;
    float* op = o + ((size_t)b * N + q0 + w * 16 + lr) * 1024 + h * 64;
#pragma unroll
    for (int c = 0; c < 4; ++c) {
        float4 v = { oacc[c][0] * linv, oacc[c][1] * linv,
                     oacc[c][2] * linv, oacc[c][3] * linv };
        *reinterpret_cast<float4*>(op + c * 16 + lg * 4) = v;
    }
}

// ---- fused residual + LayerNorm (fp32), optional bf16 copy -----------------
__global__ __launch_bounds__(256) void ln_res(const float* __restrict__ a,
                                              const float* __restrict__ r,
                                              const float* __restrict__ g,
                                              const float* __restrict__ be,
                                              float* __restrict__ y,
                                              bf16* __restrict__ yb) {
    const int row = blockIdx.x, t = threadIdx.x;
    float4 va = reinterpret_cast<const float4*>(a + (size_t)row * 1024)[t];
    float4 vr = reinterpret_cast<const float4*>(r + (size_t)row * 1024)[t];
    float v0 = va.x + vr.x, v1 = va.y + vr.y, v2 = va.z + vr.z, v3 = va.w + vr.w;
    float s1 = v0 + v1 + v2 + v3;
    float s2 = v0 * v0 + v1 * v1 + v2 * v2 + v3 * v3;
#pragma unroll
    for (int m = 1; m < 64; m <<= 1) {
        s1 += __shfl_xor(s1, m, 64);
        s2 += __shfl_xor(s2, m, 64);
    }
    __shared__ float ws1[4], ws2[4];
    if ((t & 63) == 0) { ws1[t >> 6] = s1; ws2[t >> 6] = s2; }
    __syncthreads();
    s1 = ws1[0] + ws1[1] + ws1[2] + ws1[3];
    s2 = ws2[0] + ws2[1] + ws2[2] + ws2[3];
    const float mean = s1 * (1.f / 1024.f);
    const float var = s2 * (1.f / 1024.f) - mean * mean;
    const float rstd = rsqrtf(var + 1e-5f);
    float4 gg = reinterpret_cast<const float4*>(g)[t];
    float4 bb = reinterpret_cast<const float4*>(be)[t];
    float o0 = (v0 - mean) * rstd * gg.x + bb.x;
    float o1 = (v1 - mean) * rstd * gg.y + bb.y;
    float o2 = (v2 - mean) * rstd * gg.z + bb.z;
    float o3 = (v3 - mean) * rstd * gg.w + bb.w;
    float4 out = { o0, o1, o2, o3 };
    reinterpret_cast<float4*>(y + (size_t)row * 1024)[t] = out;
    if (yb) {
        ushort4 ob = { f2b(o0), f2b(o1), f2b(o2), f2b(o3) };
        reinterpret_cast<ushort4*>(yb + (size_t)row * 1024)[t] = ob;
    }
}

// ---------------------------------------------------------------------------
extern "C" void kernel_launch(void* const* d_in, const int* in_sizes, int n_in,
                              void* d_out, int out_size, void* d_ws, size_t ws_size,
                              hipStream_t stream) {
    const float* x_in = (const float*)d_in[0];
    const float* Wqkv = (const float*)d_in[1];
    const float* bqkv = (const float*)d_in[2];
    const float* W1   = (const float*)d_in[3];
    const float* b1   = (const float*)d_in[4];
    const float* W2   = (const float*)d_in[5];
    const float* b2   = (const float*)d_in[6];
    const float* g1   = (const float*)d_in[7];
    const float* be1  = (const float*)d_in[8];
    const float* g2   = (const float*)d_in[9];
    const float* be2  = (const float*)d_in[10];

    const int Bv = 2, N = 2048, L = 4, Hh = 16;
    const int R = Bv * N;  // 4096 token rows

    char* p = (char*)d_ws;
    auto alloc = [&](size_t bytes) { char* r = p; p += (bytes + 255) & ~(size_t)255; return r; };
    bf16*  Wqkvt = (bf16*)alloc((size_t)L * 3072 * 1024 * 2);
    bf16*  W1t   = (bf16*)alloc((size_t)L * 4096 * 1024 * 2);
    bf16*  W2t   = (bf16*)alloc((size_t)L * 1024 * 4096 * 2);
    bf16*  xb    = (bf16*)alloc((size_t)R * 1024 * 2);
    bf16*  qkvb  = (bf16*)alloc((size_t)R * 3072 * 2);
    float* obuf  = (float*)alloc((size_t)R * 1024 * 4);
    float* hbuf  = (float*)alloc((size_t)R * 1024 * 4);
    bf16*  hb    = (bf16*)alloc((size_t)R * 1024 * 2);
    bf16*  f1b   = (bf16*)alloc((size_t)R * 4096 * 2);
    float* xcur  = (float*)alloc((size_t)R * 1024 * 4);
    float* f2buf = obuf;        // obuf dead after LN1 -> reuse for f2
    bf16*  vtg   = (bf16*)hbuf; // 8.4MB V^T; hbuf region dead during qkv-gemm/attn
    // split-K bf16 partials (4 x R x 1024 bf16 = 33.55MB) alias xb+qkvb:
    // both are dead during the f2/reduce window; LN2 rewrites xb afterwards.
    bf16*  part  = xb;

    transpose_cast<<<dim3(3072 / 32, 1024 / 32, L), dim3(32, 8), 0, stream>>>(Wqkv, Wqkvt, 1024, 3072);
    transpose_cast<<<dim3(4096 / 32, 1024 / 32, L), dim3(32, 8), 0, stream>>>(W1, W1t, 1024, 4096);
    transpose_cast<<<dim3(1024 / 32, 4096 / 32, L), dim3(32, 8), 0, stream>>>(W2, W2t, 4096, 1024);
    cast_bf16_k<<<(R * 1024 / 4 + 255) / 256, 256, 0, stream>>>(x_in, xb, R * 1024 / 4);

    const float* xres = x_in;
    for (int l = 0; l < L; ++l) {
        // qkv = x @ Wqkv + bqkv  -> bf16  (128x128 kernel, 768 blocks)
        gemm_bf16<0><<<(3072 / 128) * (R / 128), 256, 0, stream>>>(
            xb, Wqkvt + (size_t)l * 3072 * 1024, bqkv + l * 3072, qkvb, R, 3072, 1024, 3072 / 128);
        // V^T per (b,h): [dh][N]
        vtrans<<<dim3(N / 32, 2, Bv * Hh), dim3(32, 8), 0, stream>>>(qkvb, vtg, N);
        // o = softmax(q k^T / 32) v
        attn_fwd<<<(N / 64) * (Bv * Hh), 256, 0, stream>>>(qkvb, vtg, obuf, N);
        // h = LN(o + x)   (overwrites vtg region -- attn already done)
        ln_res<<<R, 256, 0, stream>>>(obuf, xres, g1 + l * 1024, be1 + l * 1024, hbuf, hb);
        // f1 = gelu(h @ W1 + b1) -> bf16  (256x256 pipelined, 256 blocks)
        gemm256<1><<<(R / 256) * (4096 / 256), 512, 0, stream>>>(
            hb, W1t + (size_t)l * 4096 * 1024, b1 + l * 4096, f1b,
            R, 4096, 1024, 4096 / 256, (R / 256) * (4096 / 256), 1024);
        // f2 partials: f1 @ W2 split-K=4 -> bf16 (256x256 pipelined, 64*4 blocks)
        gemm256<3><<<(R / 256) * (1024 / 256) * 4, 512, 0, stream>>>(
            f1b, W2t + (size_t)l * 1024 * 4096, nullptr, part,
            R, 1024, 1024, 1024 / 256, (R / 256) * (1024 / 256), 4096);
        // f2 = gelu(sum partials + b2) -> fp32
        reduce4_gelu<<<(R * 1024 / 8 + 255) / 256, 256, 0, stream>>>(
            part, b2 + l * 1024, f2buf, R * 1024 / 8, 1024 / 8, (size_t)R * 1024);
        // x = LN(f2 + h), also emit bf16 copy for next layer's GEMM
        float* xn = (l == L - 1) ? (float*)d_out : xcur;
        ln_res<<<R, 256, 0, stream>>>(f2buf, hbuf, g2 + l * 1024, be2 + l * 1024, xn, xb);
        xres = xn;
    }
}

// Round 11
// 1098.195 us; speedup vs baseline: 1.1432x; 1.0310x over previous
//
#include <hip/hip_runtime.h>
#include <hip/hip_bf16.h>
#include <cmath>

// ---------------------------------------------------------------------------
// TextEncoder: 4-layer post-LN transformer, B=2 N=2048 D=1024 H=16 dh=64 FF=4096
// R10: attn -> QBLK=128 (each K/V ds_read feeds 2 MFMAs; LDS ops halve; grid
// 512 = 2 blocks/CU single round) + double-buffered K/V with T14 async staging
// (one barrier per tile). qkv GEMM -> pipelined gemm256 (bias-only epilogue).
// ---------------------------------------------------------------------------

typedef __attribute__((ext_vector_type(8))) short bf16x8;
typedef __attribute__((ext_vector_type(4))) float f32x4;
typedef __hip_bfloat16 bf16;

#define DEV static __device__ __forceinline__

DEV unsigned short f2b(float f) {
    bf16 h = __float2bfloat16(f);
    return *reinterpret_cast<unsigned short*>(&h);
}

DEV unsigned int pack_bf16(float lo, float hi) {
    return (unsigned int)f2b(lo) | ((unsigned int)f2b(hi) << 16);
}

DEV float b2f(unsigned short u) {
    unsigned int x = ((unsigned int)u) << 16;
    return *reinterpret_cast<float*>(&x);
}

// tanh-form gelu: max abs deviation from exact ~1e-3, ~10 VALU ops.
DEV float gelu_fast(float x) {
    float u = 0.7978845608028654f * fmaf(0.044715f * x, x * x, x);
    u = fminf(fmaxf(u, -15.f), 15.f);               // v_med3; keeps exp2 finite
    float t = __builtin_amdgcn_exp2f(u * 2.8853900817779268f);  // e^(2u)
    float th = (t - 1.0f) * __builtin_amdgcn_rcpf(t + 1.0f);    // tanh(u)
    return 0.5f * x * (1.0f + th);
}

DEV void gload_lds16(const bf16* g, bf16* l) {
    __builtin_amdgcn_global_load_lds(
        (const __attribute__((address_space(1))) void*)g,
        (__attribute__((address_space(3))) void*)l, 16, 0, 0);
}

// ---- weight transpose + cast: Wt[l][n][k] = (bf16) W[l][k][n] --------------
__global__ __launch_bounds__(256) void transpose_cast(const float* __restrict__ W,
                                                      bf16* __restrict__ Wt,
                                                      int K, int Nm) {
    __shared__ float tile[32][33];
    const int l = blockIdx.z;
    const float* Wl = W + (size_t)l * K * Nm;
    bf16* Wtl = Wt + (size_t)l * K * Nm;
    const int n0 = blockIdx.x * 32, k0 = blockIdx.y * 32;
    const int tx = threadIdx.x, ty = threadIdx.y;
#pragma unroll
    for (int i = 0; i < 4; ++i)
        tile[ty + 8 * i][tx] = Wl[(size_t)(k0 + ty + 8 * i) * Nm + n0 + tx];
    __syncthreads();
#pragma unroll
    for (int i = 0; i < 4; ++i)
        Wtl[(size_t)(n0 + ty + 8 * i) * K + k0 + tx] = __float2bfloat16(tile[tx][ty + 8 * i]);
}

// ---- V transpose: qkv[b,n,2048+h*64+d] -> vtg[(b*16+h)*64+d][n]  (bf16) ----
__global__ __launch_bounds__(256) void vtrans(const bf16* __restrict__ qkv,
                                              bf16* __restrict__ vtg, int N) {
    __shared__ bf16 tile[32][33];
    const int bh = blockIdx.z, b = bh >> 4, h = bh & 15;
    const int n0 = blockIdx.x * 32, d0 = blockIdx.y * 32;
    const int tx = threadIdx.x, ty = threadIdx.y;
    const bf16* src = qkv + (size_t)(b * N + n0) * 3072 + 2048 + h * 64 + d0;
#pragma unroll
    for (int i = 0; i < 4; ++i)
        tile[ty + 8 * i][tx] = src[(size_t)(ty + 8 * i) * 3072 + tx];
    __syncthreads();
    bf16* dst = vtg + ((size_t)bh * 64 + d0) * N + n0;
#pragma unroll
    for (int i = 0; i < 4; ++i)
        dst[(size_t)(ty + 8 * i) * N + tx] = tile[tx][ty + 8 * i];
}

// ---- elementwise fp32 -> bf16 ----------------------------------------------
__global__ __launch_bounds__(256) void cast_bf16_k(const float* __restrict__ in,
                                                   bf16* __restrict__ out, int n4) {
    int i = blockIdx.x * 256 + threadIdx.x;
    if (i >= n4) return;
    float4 v = reinterpret_cast<const float4*>(in)[i];
    ushort4 o = { f2b(v.x), f2b(v.y), f2b(v.z), f2b(v.w) };
    reinterpret_cast<ushort4*>(out)[i] = o;
}

// ---- 256x256 pipelined GEMM (counted vmcnt + raw barriers), 8 waves --------
// EPI: 0 = bias -> bf16; 1 = bias+gelu -> bf16; 3 = raw bf16 partial (split-K).
// Grid 1D = ntiles * nsplit, XCD-chunked (grid % 8 == 0).
// K = per-split depth; Ktotal = full row stride of A / Bt.
template <int EPI>
__global__ __launch_bounds__(512, 2) void gemm256(const bf16* __restrict__ A,
                                                  const bf16* __restrict__ Bt,
                                                  const float* __restrict__ bias,
                                                  void* __restrict__ Cout,
                                                  int M, int Nm, int K,
                                                  int nbx, int ntiles, int Ktotal) {
    __shared__ bf16 As[2][256][64];   // 64 KB
    __shared__ bf16 Bs[2][256][64];   // 64 KB
    const int nwg = gridDim.x;
    int id = blockIdx.x;
    id = (id & 7) * (nwg >> 3) + (id >> 3);          // bijective: nwg % 8 == 0
    const int tile = id % ntiles, split = id / ntiles;
    const int m0 = (tile / nbx) * 256, n0 = (tile % nbx) * 256;
    const int kbase = split * K;
    const int t = threadIdx.x, w = t >> 6, lane = t & 63;
    const int wm = w >> 2, wn = w & 3;               // 2 x 4 wave grid
    const int lr = lane & 15, lg = lane >> 4;
    const int srow = w * 8;                          // wave-uniform staging row base
    const bf16* Ag = A + (size_t)(m0 + srow + (lane >> 3)) * Ktotal + kbase + (lane & 7) * 8;
    const bf16* Bg = Bt + (size_t)(n0 + srow + (lane >> 3)) * Ktotal + kbase + (lane & 7) * 8;

    f32x4 acc[8][4] = {};
    const int NT = K / 64;

    // stage K-tile kt (64 cols) into buffer b: 4 A passes + 4 B passes
#define STAGE256(kt, b)                                                          \
    {                                                                            \
        const size_t koff = (size_t)(kt) * 64;                                   \
        _Pragma("unroll")                                                        \
        for (int p = 0; p < 4; ++p)                                              \
            gload_lds16(Ag + (size_t)(p * 64) * Ktotal + koff,                   \
                        &As[b][p * 64 + srow][0]);                               \
        _Pragma("unroll")                                                        \
        for (int p = 0; p < 4; ++p)                                              \
            gload_lds16(Bg + (size_t)(p * 64) * Ktotal + koff,                   \
                        &Bs[b][p * 64 + srow][0]);                               \
    }

    STAGE256(0, 0);
    for (int kt = 0; kt < NT; ++kt) {
        const int buf = kt & 1;
        if (kt + 1 < NT) {
            STAGE256(kt + 1, buf ^ 1);
            asm volatile("s_waitcnt vmcnt(8)" ::: "memory");  // stage(kt) landed
        } else {
            asm volatile("s_waitcnt vmcnt(0)" ::: "memory");
        }
        __builtin_amdgcn_sched_barrier(0);
        __builtin_amdgcn_s_barrier();                          // all waves: tile kt ready
        __builtin_amdgcn_sched_barrier(0);
        __builtin_amdgcn_s_setprio(1);
#pragma unroll
        for (int kk = 0; kk < 2; ++kk) {
            const int lk = kk * 32 + lg * 8;
            bf16x8 a[8], b[4];
#pragma unroll
            for (int m = 0; m < 8; ++m)
                a[m] = *reinterpret_cast<const bf16x8*>(&As[buf][wm * 128 + m * 16 + lr][lk]);
#pragma unroll
            for (int n = 0; n < 4; ++n)
                b[n] = *reinterpret_cast<const bf16x8*>(&Bs[buf][wn * 64 + n * 16 + lr][lk]);
#pragma unroll
            for (int m = 0; m < 8; ++m)
#pragma unroll
                for (int n = 0; n < 4; ++n)
                    acc[m][n] = __builtin_amdgcn_mfma_f32_16x16x32_bf16(a[m], b[n], acc[m][n], 0, 0, 0);
        }
        __builtin_amdgcn_s_setprio(0);
        __builtin_amdgcn_sched_barrier(0);
        __builtin_amdgcn_s_barrier();                          // reads of buf done
        __builtin_amdgcn_sched_barrier(0);
    }
#undef STAGE256

    if (EPI == 3) {
        bf16* outp = (bf16*)Cout + (size_t)split * M * Nm;
#pragma unroll
        for (int n = 0; n < 4; ++n) {
            const int col = n0 + wn * 64 + n * 16 + lr;
#pragma unroll
            for (int m = 0; m < 8; ++m) {
                const int row = m0 + wm * 128 + m * 16 + lg * 4;
#pragma unroll
                for (int j = 0; j < 4; ++j)
                    outp[(size_t)(row + j) * Nm + col] = __float2bfloat16(acc[m][n][j]);
            }
        }
    } else {
#pragma unroll
        for (int n = 0; n < 4; ++n) {
            const int col = n0 + wn * 64 + n * 16 + lr;
            const float bc = bias[col];
#pragma unroll
            for (int m = 0; m < 8; ++m) {
                const int row = m0 + wm * 128 + m * 16 + lg * 4;
#pragma unroll
                for (int j = 0; j < 4; ++j) {
                    float v = acc[m][n][j] + bc;
                    if (EPI == 1) v = gelu_fast(v);
                    reinterpret_cast<bf16*>(Cout)[(size_t)(row + j) * Nm + col] = __float2bfloat16(v);
                }
            }
        }
    }
}

// ---- split-K reduce: out = gelu(p0+p1+p2+p3 + bias)  (bf16 partials) -------
__global__ __launch_bounds__(256) void reduce4_gelu(const bf16* __restrict__ part,
                                                    const float* __restrict__ bias,
                                                    float* __restrict__ out,
                                                    int n8, int Nm8, size_t stride) {
    int i = blockIdx.x * 256 + threadIdx.x;
    if (i >= n8) return;
    const int cb = (i % Nm8) * 8;
    float s[8];
#pragma unroll
    for (int e = 0; e < 8; ++e) s[e] = bias[cb + e];
#pragma unroll
    for (int k = 0; k < 4; ++k) {
        bf16x8 v = *reinterpret_cast<const bf16x8*>(part + (size_t)k * stride + (size_t)i * 8);
#pragma unroll
        for (int e = 0; e < 8; ++e) s[e] += b2f((unsigned short)v[e]);
    }
    float4 r0 = { gelu_fast(s[0]), gelu_fast(s[1]), gelu_fast(s[2]), gelu_fast(s[3]) };
    float4 r1 = { gelu_fast(s[4]), gelu_fast(s[5]), gelu_fast(s[6]), gelu_fast(s[7]) };
    reinterpret_cast<float4*>(out)[2 * i]     = r0;
    reinterpret_cast<float4*>(out)[2 * i + 1] = r1;
}

// ---- flash attention, swapped-operand, QBLK=128, double-buffered K/V -------
// grid 1D (N/128)*(B*H) swizzled; block 256 (4 waves); each wave owns 32 q-rows
// (2 x 16-col Q B-frags -> every K/V ds_read feeds 2 MFMAs). One barrier/tile:
// issue next-tile global loads early, compute, vmcnt(0)+ds_write other buffer.
__global__ __launch_bounds__(256) void attn_fwd(const bf16* __restrict__ qkv,
                                                const bf16* __restrict__ vtg,
                                                float* __restrict__ o, int N) {
    __shared__ bf16 Ks[2][64][72];   // K tiles [kv][dh], padded
    __shared__ bf16 Vs[2][64][72];   // V^T tiles [dh][kv], padded
    __shared__ bf16 Ps[4][32][72];   // per-wave P [q][kv], padded
    const int nwg = gridDim.x, nbx = N / 128;
    int id = blockIdx.x;
    id = (id & 7) * (nwg >> 3) + (id >> 3);  // XCD-chunked
    const int bh = id / nbx, b = bh >> 4, h = bh & 15;
    const int q0 = (id % nbx) * 128;
    const int t = threadIdx.x, w = t >> 6, lane = t & 63;
    const int lr = lane & 15, lg = lane >> 4;
    const bf16* base = qkv + (size_t)b * N * 3072;
    const bf16* vbase = vtg + (size_t)bh * 64 * N;

    // Q as B-operand: col q = lr (per rb block), k = 32f + 8lg + i
    bf16x8 qf[2][2];
#pragma unroll
    for (int rb = 0; rb < 2; ++rb) {
        const bf16* qp = base + (size_t)(q0 + w * 32 + rb * 16 + lr) * 3072 + h * 64 + lg * 8;
        qf[rb][0] = *reinterpret_cast<const bf16x8*>(qp);
        qf[rb][1] = *reinterpret_cast<const bf16x8*>(qp + 32);
    }

    float mrow[2] = { -INFINITY, -INFINITY };
    float lrow[2] = { 0.f, 0.f };
    f32x4 oacc[2][4] = {};
    const float scale2 = 0.03125f * 1.44269504088896340736f;  // embedDim^-0.5 * log2(e)
    const int srow = t >> 2, scolb = (t & 3) * 8;

    const bf16* kptr = base + (size_t)srow * 3072 + 1024 + h * 64 + scolb;
    const bf16* vptr = vbase + (size_t)srow * N + scolb;

    // prologue: stage tile 0 into buffer 0
    uint4 k0 = *reinterpret_cast<const uint4*>(kptr);
    uint4 k1 = *reinterpret_cast<const uint4*>(kptr + 32);
    uint4 v0 = *reinterpret_cast<const uint4*>(vptr);
    uint4 v1 = *reinterpret_cast<const uint4*>(vptr + 32);
    *reinterpret_cast<uint4*>(&Ks[0][srow][scolb])      = k0;
    *reinterpret_cast<uint4*>(&Ks[0][srow][scolb + 32]) = k1;
    *reinterpret_cast<uint4*>(&Vs[0][srow][scolb])      = v0;
    *reinterpret_cast<uint4*>(&Vs[0][srow][scolb + 32]) = v1;

    int cur = 0;
    for (int kv0 = 0; kv0 < N; kv0 += 64) {
        __syncthreads();   // buf[cur] writes visible; all reads of buf[cur^1] done
        const bool more = (kv0 + 64) < N;
        if (more) {        // issue next tile's loads early (latency hides under compute)
            const bf16* kn = kptr + (size_t)(kv0 + 64) * 3072;
            const bf16* vn = vptr + (kv0 + 64);
            k0 = *reinterpret_cast<const uint4*>(kn);
            k1 = *reinterpret_cast<const uint4*>(kn + 32);
            v0 = *reinterpret_cast<const uint4*>(vn);
            v1 = *reinterpret_cast<const uint4*>(vn + 32);
        }
        __builtin_amdgcn_sched_barrier(0);

        // S^T[kv][q] = K @ Q^T : each K-frag feeds both rb blocks
        f32x4 st[2][4] = {};
#pragma unroll
        for (int f = 0; f < 2; ++f)
#pragma unroll
            for (int c = 0; c < 4; ++c) {
                bf16x8 ka = *reinterpret_cast<const bf16x8*>(&Ks[cur][c * 16 + lr][f * 32 + lg * 8]);
                st[0][c] = __builtin_amdgcn_mfma_f32_16x16x32_bf16(ka, qf[0][f], st[0][c], 0, 0, 0);
                st[1][c] = __builtin_amdgcn_mfma_f32_16x16x32_bf16(ka, qf[1][f], st[1][c], 0, 0, 0);
            }

        // softmax per rb (lane-local 16 kv values, exp2 domain, defer-max)
#pragma unroll
        for (int rb = 0; rb < 2; ++rb) {
            float smax = st[rb][0][0];
#pragma unroll
            for (int c = 0; c < 4; ++c)
#pragma unroll
                for (int j = 0; j < 4; ++j) smax = fmaxf(smax, st[rb][c][j]);
            const float tilemax = smax * scale2;
            if (!__all(tilemax - mrow[rb] <= 11.0f)) {
                float tm = fmaxf(tilemax, __shfl_xor(tilemax, 16, 64));
                tm = fmaxf(tm, __shfl_xor(tm, 32, 64));
                const float mnew = fmaxf(mrow[rb], tm);
                const float al = __builtin_amdgcn_exp2f(mrow[rb] - mnew);
                mrow[rb] = mnew;
                lrow[rb] *= al;
#pragma unroll
                for (int c = 0; c < 4; ++c)
#pragma unroll
                    for (int j = 0; j < 4; ++j) oacc[rb][c][j] *= al;
            }
            float p[4][4];
            float psum = 0.f;
#pragma unroll
            for (int c = 0; c < 4; ++c)
#pragma unroll
                for (int j = 0; j < 4; ++j) {
                    p[c][j] = __builtin_amdgcn_exp2f(fmaf(st[rb][c][j], scale2, -mrow[rb]));
                    psum += p[c][j];
                }
            psum += __shfl_xor(psum, 16, 64);
            psum += __shfl_xor(psum, 32, 64);
            lrow[rb] += psum;
#pragma unroll
            for (int c = 0; c < 4; ++c) {
                uint2 pr = { pack_bf16(p[c][0], p[c][1]), pack_bf16(p[c][2], p[c][3]) };
                *reinterpret_cast<uint2*>(&Ps[w][rb * 16 + lr][c * 16 + lg * 4]) = pr;
            }
        }
        asm volatile("s_waitcnt lgkmcnt(0)" ::: "memory");  // in-wave Ps write->read
        __builtin_amdgcn_sched_barrier(0);

        // O^T += V^T @ P^T : each V-frag feeds both rb blocks
#pragma unroll
        for (int f = 0; f < 2; ++f) {
            bf16x8 pb0 = *reinterpret_cast<const bf16x8*>(&Ps[w][lr][f * 32 + lg * 8]);
            bf16x8 pb1 = *reinterpret_cast<const bf16x8*>(&Ps[w][16 + lr][f * 32 + lg * 8]);
#pragma unroll
            for (int c = 0; c < 4; ++c) {
                bf16x8 va = *reinterpret_cast<const bf16x8*>(&Vs[cur][c * 16 + lr][f * 32 + lg * 8]);
                oacc[0][c] = __builtin_amdgcn_mfma_f32_16x16x32_bf16(va, pb0, oacc[0][c], 0, 0, 0);
                oacc[1][c] = __builtin_amdgcn_mfma_f32_16x16x32_bf16(va, pb1, oacc[1][c], 0, 0, 0);
            }
        }

        if (more) {   // loads have had the whole compute to land; write other buffer
            asm volatile("s_waitcnt vmcnt(0)" ::: "memory");
            __builtin_amdgcn_sched_barrier(0);
            *reinterpret_cast<uint4*>(&Ks[cur ^ 1][srow][scolb])      = k0;
            *reinterpret_cast<uint4*>(&Ks[cur ^ 1][srow][scolb + 32]) = k1;
            *reinterpret_cast<uint4*>(&Vs[cur ^ 1][srow][scolb])      = v0;
            *reinterpret_cast<uint4*>(&Vs[cur ^ 1][srow][scolb + 32]) = v1;
        }
        cur ^= 1;
    }

    // O^T layout: col q = lr, row d = 16c + 4lg + j -> float4 stores
#pragma unroll
    for (int rb = 0; rb < 2; ++rb) {
        const float linv = 1.f / lrow[rb];
        float* op = o + ((size_t)b * N + q0 + w * 32 + rb * 16 + lr) * 1024 + h * 64;
#pragma unroll
        for (int c = 0; c < 4; ++c) {
            float4 v = { oacc[rb][c][0] * linv, oacc[rb][c][1] * linv,
                         oacc[rb][c][2] * linv, oacc[rb][c][3] * linv };
            *reinterpret_cast<float4*>(op + c * 16 + lg * 4) = v;
        }
    }
}

// ---- fused residual + LayerNorm (fp32), optional bf16 copy -----------------
__global__ __launch_bounds__(256) void ln_res(const float* __restrict__ a,
                                              const float* __restrict__ r,
                                              const float* __restrict__ g,
                                              const float* __restrict__ be,
                                              float* __restrict__ y,
                                              bf16* __restrict__ yb) {
    const int row = blockIdx.x, t = threadIdx.x;
    float4 va = reinterpret_cast<const float4*>(a + (size_t)row * 1024)[t];
    float4 vr = reinterpret_cast<const float4*>(r + (size_t)row * 1024)[t];
    float v0 = va.x + vr.x, v1 = va.y + vr.y, v2 = va.z + vr.z, v3 = va.w + vr.w;
    float s1 = v0 + v1 + v2 + v3;
    float s2 = v0 * v0 + v1 * v1 + v2 * v2 + v3 * v3;
#pragma unroll
    for (int m = 1; m < 64; m <<= 1) {
        s1 += __shfl_xor(s1, m, 64);
        s2 += __shfl_xor(s2, m, 64);
    }
    __shared__ float ws1[4], ws2[4];
    if ((t & 63) == 0) { ws1[t >> 6] = s1; ws2[t >> 6] = s2; }
    __syncthreads();
    s1 = ws1[0] + ws1[1] + ws1[2] + ws1[3];
    s2 = ws2[0] + ws2[1] + ws2[2] + ws2[3];
    const float mean = s1 * (1.f / 1024.f);
    const float var = s2 * (1.f / 1024.f) - mean * mean;
    const float rstd = rsqrtf(var + 1e-5f);
    float4 gg = reinterpret_cast<const float4*>(g)[t];
    float4 bb = reinterpret_cast<const float4*>(be)[t];
    float o0 = (v0 - mean) * rstd * gg.x + bb.x;
    float o1 = (v1 - mean) * rstd * gg.y + bb.y;
    float o2 = (v2 - mean) * rstd * gg.z + bb.z;
    float o3 = (v3 - mean) * rstd * gg.w + bb.w;
    float4 out = { o0, o1, o2, o3 };
    reinterpret_cast<float4*>(y + (size_t)row * 1024)[t] = out;
    if (yb) {
        ushort4 ob = { f2b(o0), f2b(o1), f2b(o2), f2b(o3) };
        reinterpret_cast<ushort4*>(yb + (size_t)row * 1024)[t] = ob;
    }
}

// ---------------------------------------------------------------------------
extern "C" void kernel_launch(void* const* d_in, const int* in_sizes, int n_in,
                              void* d_out, int out_size, void* d_ws, size_t ws_size,
                              hipStream_t stream) {
    const float* x_in = (const float*)d_in[0];
    const float* Wqkv = (const float*)d_in[1];
    const float* bqkv = (const float*)d_in[2];
    const float* W1   = (const float*)d_in[3];
    const float* b1   = (const float*)d_in[4];
    const float* W2   = (const float*)d_in[5];
    const float* b2   = (const float*)d_in[6];
    const float* g1   = (const float*)d_in[7];
    const float* be1  = (const float*)d_in[8];
    const float* g2   = (const float*)d_in[9];
    const float* be2  = (const float*)d_in[10];

    const int Bv = 2, N = 2048, L = 4, Hh = 16;
    const int R = Bv * N;  // 4096 token rows

    char* p = (char*)d_ws;
    auto alloc = [&](size_t bytes) { char* r = p; p += (bytes + 255) & ~(size_t)255; return r; };
    bf16*  Wqkvt = (bf16*)alloc((size_t)L * 3072 * 1024 * 2);
    bf16*  W1t   = (bf16*)alloc((size_t)L * 4096 * 1024 * 2);
    bf16*  W2t   = (bf16*)alloc((size_t)L * 1024 * 4096 * 2);
    bf16*  xb    = (bf16*)alloc((size_t)R * 1024 * 2);
    bf16*  qkvb  = (bf16*)alloc((size_t)R * 3072 * 2);
    float* obuf  = (float*)alloc((size_t)R * 1024 * 4);
    float* hbuf  = (float*)alloc((size_t)R * 1024 * 4);
    bf16*  hb    = (bf16*)alloc((size_t)R * 1024 * 2);
    bf16*  f1b   = (bf16*)alloc((size_t)R * 4096 * 2);
    float* xcur  = (float*)alloc((size_t)R * 1024 * 4);
    float* f2buf = obuf;        // obuf dead after LN1 -> reuse for f2
    bf16*  vtg   = (bf16*)hbuf; // 8.4MB V^T; hbuf region dead during qkv-gemm/attn
    // split-K bf16 partials (4 x R x 1024 bf16 = 33.55MB) alias xb+qkvb:
    // both are dead during the f2/reduce window; LN2 rewrites xb afterwards.
    bf16*  part  = xb;

    transpose_cast<<<dim3(3072 / 32, 1024 / 32, L), dim3(32, 8), 0, stream>>>(Wqkv, Wqkvt, 1024, 3072);
    transpose_cast<<<dim3(4096 / 32, 1024 / 32, L), dim3(32, 8), 0, stream>>>(W1, W1t, 1024, 4096);
    transpose_cast<<<dim3(1024 / 32, 4096 / 32, L), dim3(32, 8), 0, stream>>>(W2, W2t, 4096, 1024);
    cast_bf16_k<<<(R * 1024 / 4 + 255) / 256, 256, 0, stream>>>(x_in, xb, R * 1024 / 4);

    const float* xres = x_in;
    for (int l = 0; l < L; ++l) {
        // qkv = x @ Wqkv + bqkv  -> bf16  (256x256 pipelined, 192 blocks)
        gemm256<0><<<(R / 256) * (3072 / 256), 512, 0, stream>>>(
            xb, Wqkvt + (size_t)l * 3072 * 1024, bqkv + l * 3072, qkvb,
            R, 3072, 1024, 3072 / 256, (R / 256) * (3072 / 256), 1024);
        // V^T per (b,h): [dh][N]
        vtrans<<<dim3(N / 32, 2, Bv * Hh), dim3(32, 8), 0, stream>>>(qkvb, vtg, N);
        // o = softmax(q k^T / 32) v   (QBLK=128, 512 blocks = 2/CU)
        attn_fwd<<<(N / 128) * (Bv * Hh), 256, 0, stream>>>(qkvb, vtg, obuf, N);
        // h = LN(o + x)   (overwrites vtg region -- attn already done)
        ln_res<<<R, 256, 0, stream>>>(obuf, xres, g1 + l * 1024, be1 + l * 1024, hbuf, hb);
        // f1 = gelu(h @ W1 + b1) -> bf16  (256x256 pipelined, 256 blocks)
        gemm256<1><<<(R / 256) * (4096 / 256), 512, 0, stream>>>(
            hb, W1t + (size_t)l * 4096 * 1024, b1 + l * 4096, f1b,
            R, 4096, 1024, 4096 / 256, (R / 256) * (4096 / 256), 1024);
        // f2 partials: f1 @ W2 split-K=4 -> bf16 (256x256 pipelined, 64*4 blocks)
        gemm256<3><<<(R / 256) * (1024 / 256) * 4, 512, 0, stream>>>(
            f1b, W2t + (size_t)l * 1024 * 4096, nullptr, part,
            R, 1024, 1024, 1024 / 256, (R / 256) * (1024 / 256), 4096);
        // f2 = gelu(sum partials + b2) -> fp32
        reduce4_gelu<<<(R * 1024 / 8 + 255) / 256, 256, 0, stream>>>(
            part, b2 + l * 1024, f2buf, R * 1024 / 8, 1024 / 8, (size_t)R * 1024);
        // x = LN(f2 + h), also emit bf16 copy for next layer's GEMM
        float* xn = (l == L - 1) ? (float*)d_out : xcur;
        ln_res<<<R, 256, 0, stream>>>(f2buf, hbuf, g2 + l * 1024, be2 + l * 1024, xn, xb);
        xres = xn;
    }
}

// Round 12
// 1063.430 us; speedup vs baseline: 1.1806x; 1.0327x over previous
//
#include <hip/hip_runtime.h>
#include <hip/hip_bf16.h>
#include <cmath>

// ---------------------------------------------------------------------------
// TextEncoder: 4-layer post-LN transformer, B=2 N=2048 D=1024 H=16 dh=64 FF=4096
// R11: launch-graph slimming. (1) V-transpose fused into qkv GEMM epilogue
// (EPI=4 writes V tiles transposed into vtg; vtrans kernel deleted).
// (2) split-K reduce + gelu fused into LN2 (ln_res_red4; reduce4_gelu and the
// f2buf round-trip deleted). Partials moved to dead obuf/qkvb regions.
// ---------------------------------------------------------------------------

typedef __attribute__((ext_vector_type(8))) short bf16x8;
typedef __attribute__((ext_vector_type(4))) float f32x4;
typedef __hip_bfloat16 bf16;

#define DEV static __device__ __forceinline__

DEV unsigned short f2b(float f) {
    bf16 h = __float2bfloat16(f);
    return *reinterpret_cast<unsigned short*>(&h);
}

DEV unsigned int pack_bf16(float lo, float hi) {
    return (unsigned int)f2b(lo) | ((unsigned int)f2b(hi) << 16);
}

DEV float b2f(unsigned short u) {
    unsigned int x = ((unsigned int)u) << 16;
    return *reinterpret_cast<float*>(&x);
}

// tanh-form gelu: max abs deviation from exact ~1e-3, ~10 VALU ops.
DEV float gelu_fast(float x) {
    float u = 0.7978845608028654f * fmaf(0.044715f * x, x * x, x);
    u = fminf(fmaxf(u, -15.f), 15.f);               // v_med3; keeps exp2 finite
    float t = __builtin_amdgcn_exp2f(u * 2.8853900817779268f);  // e^(2u)
    float th = (t - 1.0f) * __builtin_amdgcn_rcpf(t + 1.0f);    // tanh(u)
    return 0.5f * x * (1.0f + th);
}

DEV void gload_lds16(const bf16* g, bf16* l) {
    __builtin_amdgcn_global_load_lds(
        (const __attribute__((address_space(1))) void*)g,
        (__attribute__((address_space(3))) void*)l, 16, 0, 0);
}

// ---- weight transpose + cast: Wt[l][n][k] = (bf16) W[l][k][n] --------------
__global__ __launch_bounds__(256) void transpose_cast(const float* __restrict__ W,
                                                      bf16* __restrict__ Wt,
                                                      int K, int Nm) {
    __shared__ float tile[32][33];
    const int l = blockIdx.z;
    const float* Wl = W + (size_t)l * K * Nm;
    bf16* Wtl = Wt + (size_t)l * K * Nm;
    const int n0 = blockIdx.x * 32, k0 = blockIdx.y * 32;
    const int tx = threadIdx.x, ty = threadIdx.y;
#pragma unroll
    for (int i = 0; i < 4; ++i)
        tile[ty + 8 * i][tx] = Wl[(size_t)(k0 + ty + 8 * i) * Nm + n0 + tx];
    __syncthreads();
#pragma unroll
    for (int i = 0; i < 4; ++i)
        Wtl[(size_t)(n0 + ty + 8 * i) * K + k0 + tx] = __float2bfloat16(tile[tx][ty + 8 * i]);
}

// ---- elementwise fp32 -> bf16 ----------------------------------------------
__global__ __launch_bounds__(256) void cast_bf16_k(const float* __restrict__ in,
                                                   bf16* __restrict__ out, int n4) {
    int i = blockIdx.x * 256 + threadIdx.x;
    if (i >= n4) return;
    float4 v = reinterpret_cast<const float4*>(in)[i];
    ushort4 o = { f2b(v.x), f2b(v.y), f2b(v.z), f2b(v.w) };
    reinterpret_cast<ushort4*>(out)[i] = o;
}

// ---- 256x256 pipelined GEMM (counted vmcnt + raw barriers), 8 waves --------
// EPI: 0 = bias -> bf16; 1 = bias+gelu -> bf16; 3 = raw bf16 partials to
// Cout (splits 0,1) / Cout2 (splits 2,3); 4 = qkv: Q/K cols -> bf16 Cout,
// V cols (n0 >= 2048) -> bias + TRANSPOSED ushort4 into Cout2 (vtg layout
// [(b*16+h)*64+d][n], N=2048 hardcoded for this problem).
template <int EPI>
__global__ __launch_bounds__(512, 2) void gemm256(const bf16* __restrict__ A,
                                                  const bf16* __restrict__ Bt,
                                                  const float* __restrict__ bias,
                                                  void* __restrict__ Cout,
                                                  void* __restrict__ Cout2,
                                                  int M, int Nm, int K,
                                                  int nbx, int ntiles, int Ktotal) {
    __shared__ bf16 As[2][256][64];   // 64 KB
    __shared__ bf16 Bs[2][256][64];   // 64 KB
    const int nwg = gridDim.x;
    int id = blockIdx.x;
    id = (id & 7) * (nwg >> 3) + (id >> 3);          // bijective: nwg % 8 == 0
    const int tile = id % ntiles, split = id / ntiles;
    const int m0 = (tile / nbx) * 256, n0 = (tile % nbx) * 256;
    const int kbase = split * K;
    const int t = threadIdx.x, w = t >> 6, lane = t & 63;
    const int wm = w >> 2, wn = w & 3;               // 2 x 4 wave grid
    const int lr = lane & 15, lg = lane >> 4;
    const int srow = w * 8;                          // wave-uniform staging row base
    const bf16* Ag = A + (size_t)(m0 + srow + (lane >> 3)) * Ktotal + kbase + (lane & 7) * 8;
    const bf16* Bg = Bt + (size_t)(n0 + srow + (lane >> 3)) * Ktotal + kbase + (lane & 7) * 8;

    f32x4 acc[8][4] = {};
    const int NT = K / 64;

    // stage K-tile kt (64 cols) into buffer b: 4 A passes + 4 B passes
#define STAGE256(kt, b)                                                          \
    {                                                                            \
        const size_t koff = (size_t)(kt) * 64;                                   \
        _Pragma("unroll")                                                        \
        for (int p = 0; p < 4; ++p)                                              \
            gload_lds16(Ag + (size_t)(p * 64) * Ktotal + koff,                   \
                        &As[b][p * 64 + srow][0]);                               \
        _Pragma("unroll")                                                        \
        for (int p = 0; p < 4; ++p)                                              \
            gload_lds16(Bg + (size_t)(p * 64) * Ktotal + koff,                   \
                        &Bs[b][p * 64 + srow][0]);                               \
    }

    STAGE256(0, 0);
    for (int kt = 0; kt < NT; ++kt) {
        const int buf = kt & 1;
        if (kt + 1 < NT) {
            STAGE256(kt + 1, buf ^ 1);
            asm volatile("s_waitcnt vmcnt(8)" ::: "memory");  // stage(kt) landed
        } else {
            asm volatile("s_waitcnt vmcnt(0)" ::: "memory");
        }
        __builtin_amdgcn_sched_barrier(0);
        __builtin_amdgcn_s_barrier();                          // all waves: tile kt ready
        __builtin_amdgcn_sched_barrier(0);
        __builtin_amdgcn_s_setprio(1);
#pragma unroll
        for (int kk = 0; kk < 2; ++kk) {
            const int lk = kk * 32 + lg * 8;
            bf16x8 a[8], b[4];
#pragma unroll
            for (int m = 0; m < 8; ++m)
                a[m] = *reinterpret_cast<const bf16x8*>(&As[buf][wm * 128 + m * 16 + lr][lk]);
#pragma unroll
            for (int n = 0; n < 4; ++n)
                b[n] = *reinterpret_cast<const bf16x8*>(&Bs[buf][wn * 64 + n * 16 + lr][lk]);
#pragma unroll
            for (int m = 0; m < 8; ++m)
#pragma unroll
                for (int n = 0; n < 4; ++n)
                    acc[m][n] = __builtin_amdgcn_mfma_f32_16x16x32_bf16(a[m], b[n], acc[m][n], 0, 0, 0);
        }
        __builtin_amdgcn_s_setprio(0);
        __builtin_amdgcn_sched_barrier(0);
        __builtin_amdgcn_s_barrier();                          // reads of buf done
        __builtin_amdgcn_sched_barrier(0);
    }
#undef STAGE256

    if (EPI == 3) {
        bf16* outp = (split < 2)
            ? (bf16*)Cout + (size_t)split * M * Nm
            : (bf16*)Cout2 + (size_t)(split - 2) * M * Nm;
#pragma unroll
        for (int n = 0; n < 4; ++n) {
            const int col = n0 + wn * 64 + n * 16 + lr;
#pragma unroll
            for (int m = 0; m < 8; ++m) {
                const int row = m0 + wm * 128 + m * 16 + lg * 4;
#pragma unroll
                for (int j = 0; j < 4; ++j)
                    outp[(size_t)(row + j) * Nm + col] = __float2bfloat16(acc[m][n][j]);
            }
        }
    } else if (EPI == 4 && n0 >= 2048) {
        // V tile: write transposed into vtg[(b*1024 + (col-2048))][n], N=2048
#pragma unroll
        for (int n = 0; n < 4; ++n) {
            const int col = n0 + wn * 64 + n * 16 + lr;
            const float bc = bias[col];
            const int vcol = col - 2048;
#pragma unroll
            for (int m = 0; m < 8; ++m) {
                const int row = m0 + wm * 128 + m * 16 + lg * 4;
                const int b = row >> 11, nn = row & 2047;
                ushort4 o = { f2b(acc[m][n][0] + bc), f2b(acc[m][n][1] + bc),
                              f2b(acc[m][n][2] + bc), f2b(acc[m][n][3] + bc) };
                *reinterpret_cast<ushort4*>(
                    (bf16*)Cout2 + ((size_t)(b * 1024 + vcol)) * 2048 + nn) = o;
            }
        }
    } else {
#pragma unroll
        for (int n = 0; n < 4; ++n) {
            const int col = n0 + wn * 64 + n * 16 + lr;
            const float bc = bias[col];
#pragma unroll
            for (int m = 0; m < 8; ++m) {
                const int row = m0 + wm * 128 + m * 16 + lg * 4;
#pragma unroll
                for (int j = 0; j < 4; ++j) {
                    float v = acc[m][n][j] + bc;
                    if (EPI == 1) v = gelu_fast(v);
                    reinterpret_cast<bf16*>(Cout)[(size_t)(row + j) * Nm + col] = __float2bfloat16(v);
                }
            }
        }
    }
}

// ---- flash attention, swapped-operand, QBLK=128, double-buffered K/V -------
__global__ __launch_bounds__(256) void attn_fwd(const bf16* __restrict__ qkv,
                                                const bf16* __restrict__ vtg,
                                                float* __restrict__ o, int N) {
    __shared__ bf16 Ks[2][64][72];   // K tiles [kv][dh], padded
    __shared__ bf16 Vs[2][64][72];   // V^T tiles [dh][kv], padded
    __shared__ bf16 Ps[4][32][72];   // per-wave P [q][kv], padded
    const int nwg = gridDim.x, nbx = N / 128;
    int id = blockIdx.x;
    id = (id & 7) * (nwg >> 3) + (id >> 3);  // XCD-chunked
    const int bh = id / nbx, b = bh >> 4, h = bh & 15;
    const int q0 = (id % nbx) * 128;
    const int t = threadIdx.x, w = t >> 6, lane = t & 63;
    const int lr = lane & 15, lg = lane >> 4;
    const bf16* base = qkv + (size_t)b * N * 3072;
    const bf16* vbase = vtg + (size_t)bh * 64 * N;

    // Q as B-operand: col q = lr (per rb block), k = 32f + 8lg + i
    bf16x8 qf[2][2];
#pragma unroll
    for (int rb = 0; rb < 2; ++rb) {
        const bf16* qp = base + (size_t)(q0 + w * 32 + rb * 16 + lr) * 3072 + h * 64 + lg * 8;
        qf[rb][0] = *reinterpret_cast<const bf16x8*>(qp);
        qf[rb][1] = *reinterpret_cast<const bf16x8*>(qp + 32);
    }

    float mrow[2] = { -INFINITY, -INFINITY };
    float lrow[2] = { 0.f, 0.f };
    f32x4 oacc[2][4] = {};
    const float scale2 = 0.03125f * 1.44269504088896340736f;  // embedDim^-0.5 * log2(e)
    const int srow = t >> 2, scolb = (t & 3) * 8;

    const bf16* kptr = base + (size_t)srow * 3072 + 1024 + h * 64 + scolb;
    const bf16* vptr = vbase + (size_t)srow * N + scolb;

    // prologue: stage tile 0 into buffer 0
    uint4 k0 = *reinterpret_cast<const uint4*>(kptr);
    uint4 k1 = *reinterpret_cast<const uint4*>(kptr + 32);
    uint4 v0 = *reinterpret_cast<const uint4*>(vptr);
    uint4 v1 = *reinterpret_cast<const uint4*>(vptr + 32);
    *reinterpret_cast<uint4*>(&Ks[0][srow][scolb])      = k0;
    *reinterpret_cast<uint4*>(&Ks[0][srow][scolb + 32]) = k1;
    *reinterpret_cast<uint4*>(&Vs[0][srow][scolb])      = v0;
    *reinterpret_cast<uint4*>(&Vs[0][srow][scolb + 32]) = v1;

    int cur = 0;
    for (int kv0 = 0; kv0 < N; kv0 += 64) {
        __syncthreads();   // buf[cur] writes visible; all reads of buf[cur^1] done
        const bool more = (kv0 + 64) < N;
        if (more) {        // issue next tile's loads early (latency hides under compute)
            const bf16* kn = kptr + (size_t)(kv0 + 64) * 3072;
            const bf16* vn = vptr + (kv0 + 64);
            k0 = *reinterpret_cast<const uint4*>(kn);
            k1 = *reinterpret_cast<const uint4*>(kn + 32);
            v0 = *reinterpret_cast<const uint4*>(vn);
            v1 = *reinterpret_cast<const uint4*>(vn + 32);
        }
        __builtin_amdgcn_sched_barrier(0);

        // S^T[kv][q] = K @ Q^T : each K-frag feeds both rb blocks
        f32x4 st[2][4] = {};
#pragma unroll
        for (int f = 0; f < 2; ++f)
#pragma unroll
            for (int c = 0; c < 4; ++c) {
                bf16x8 ka = *reinterpret_cast<const bf16x8*>(&Ks[cur][c * 16 + lr][f * 32 + lg * 8]);
                st[0][c] = __builtin_amdgcn_mfma_f32_16x16x32_bf16(ka, qf[0][f], st[0][c], 0, 0, 0);
                st[1][c] = __builtin_amdgcn_mfma_f32_16x16x32_bf16(ka, qf[1][f], st[1][c], 0, 0, 0);
            }

        // softmax per rb (lane-local 16 kv values, exp2 domain, defer-max)
#pragma unroll
        for (int rb = 0; rb < 2; ++rb) {
            float smax = st[rb][0][0];
#pragma unroll
            for (int c = 0; c < 4; ++c)
#pragma unroll
                for (int j = 0; j < 4; ++j) smax = fmaxf(smax, st[rb][c][j]);
            const float tilemax = smax * scale2;
            if (!__all(tilemax - mrow[rb] <= 11.0f)) {
                float tm = fmaxf(tilemax, __shfl_xor(tilemax, 16, 64));
                tm = fmaxf(tm, __shfl_xor(tm, 32, 64));
                const float mnew = fmaxf(mrow[rb], tm);
                const float al = __builtin_amdgcn_exp2f(mrow[rb] - mnew);
                mrow[rb] = mnew;
                lrow[rb] *= al;
#pragma unroll
                for (int c = 0; c < 4; ++c)
#pragma unroll
                    for (int j = 0; j < 4; ++j) oacc[rb][c][j] *= al;
            }
            float p[4][4];
            float psum = 0.f;
#pragma unroll
            for (int c = 0; c < 4; ++c)
#pragma unroll
                for (int j = 0; j < 4; ++j) {
                    p[c][j] = __builtin_amdgcn_exp2f(fmaf(st[rb][c][j], scale2, -mrow[rb]));
                    psum += p[c][j];
                }
            psum += __shfl_xor(psum, 16, 64);
            psum += __shfl_xor(psum, 32, 64);
            lrow[rb] += psum;
#pragma unroll
            for (int c = 0; c < 4; ++c) {
                uint2 pr = { pack_bf16(p[c][0], p[c][1]), pack_bf16(p[c][2], p[c][3]) };
                *reinterpret_cast<uint2*>(&Ps[w][rb * 16 + lr][c * 16 + lg * 4]) = pr;
            }
        }
        asm volatile("s_waitcnt lgkmcnt(0)" ::: "memory");  // in-wave Ps write->read
        __builtin_amdgcn_sched_barrier(0);

        // O^T += V^T @ P^T : each V-frag feeds both rb blocks
#pragma unroll
        for (int f = 0; f < 2; ++f) {
            bf16x8 pb0 = *reinterpret_cast<const bf16x8*>(&Ps[w][lr][f * 32 + lg * 8]);
            bf16x8 pb1 = *reinterpret_cast<const bf16x8*>(&Ps[w][16 + lr][f * 32 + lg * 8]);
#pragma unroll
            for (int c = 0; c < 4; ++c) {
                bf16x8 va = *reinterpret_cast<const bf16x8*>(&Vs[cur][c * 16 + lr][f * 32 + lg * 8]);
                oacc[0][c] = __builtin_amdgcn_mfma_f32_16x16x32_bf16(va, pb0, oacc[0][c], 0, 0, 0);
                oacc[1][c] = __builtin_amdgcn_mfma_f32_16x16x32_bf16(va, pb1, oacc[1][c], 0, 0, 0);
            }
        }

        if (more) {   // loads have had the whole compute to land; write other buffer
            asm volatile("s_waitcnt vmcnt(0)" ::: "memory");
            __builtin_amdgcn_sched_barrier(0);
            *reinterpret_cast<uint4*>(&Ks[cur ^ 1][srow][scolb])      = k0;
            *reinterpret_cast<uint4*>(&Ks[cur ^ 1][srow][scolb + 32]) = k1;
            *reinterpret_cast<uint4*>(&Vs[cur ^ 1][srow][scolb])      = v0;
            *reinterpret_cast<uint4*>(&Vs[cur ^ 1][srow][scolb + 32]) = v1;
        }
        cur ^= 1;
    }

    // O^T layout: col q = lr, row d = 16c + 4lg + j -> float4 stores
#pragma unroll
    for (int rb = 0; rb < 2; ++rb) {
        const float linv = 1.f / lrow[rb];
        float* op = o + ((size_t)b * N + q0 + w * 32 + rb * 16 + lr) * 1024 + h * 64;
#pragma unroll
        for (int c = 0; c < 4; ++c) {
            float4 v = { oacc[rb][c][0] * linv, oacc[rb][c][1] * linv,
                         oacc[rb][c][2] * linv, oacc[rb][c][3] * linv };
            *reinterpret_cast<float4*>(op + c * 16 + lg * 4) = v;
        }
    }
}

// ---- fused residual + LayerNorm (fp32), optional bf16 copy -----------------
__global__ __launch_bounds__(256) void ln_res(const float* __restrict__ a,
                                              const float* __restrict__ r,
                                              const float* __restrict__ g,
                                              const float* __restrict__ be,
                                              float* __restrict__ y,
                                              bf16* __restrict__ yb) {
    const int row = blockIdx.x, t = threadIdx.x;
    float4 va = reinterpret_cast<const float4*>(a + (size_t)row * 1024)[t];
    float4 vr = reinterpret_cast<const float4*>(r + (size_t)row * 1024)[t];
    float v0 = va.x + vr.x, v1 = va.y + vr.y, v2 = va.z + vr.z, v3 = va.w + vr.w;
    float s1 = v0 + v1 + v2 + v3;
    float s2 = v0 * v0 + v1 * v1 + v2 * v2 + v3 * v3;
#pragma unroll
    for (int m = 1; m < 64; m <<= 1) {
        s1 += __shfl_xor(s1, m, 64);
        s2 += __shfl_xor(s2, m, 64);
    }
    __shared__ float ws1[4], ws2[4];
    if ((t & 63) == 0) { ws1[t >> 6] = s1; ws2[t >> 6] = s2; }
    __syncthreads();
    s1 = ws1[0] + ws1[1] + ws1[2] + ws1[3];
    s2 = ws2[0] + ws2[1] + ws2[2] + ws2[3];
    const float mean = s1 * (1.f / 1024.f);
    const float var = s2 * (1.f / 1024.f) - mean * mean;
    const float rstd = rsqrtf(var + 1e-5f);
    float4 gg = reinterpret_cast<const float4*>(g)[t];
    float4 bb = reinterpret_cast<const float4*>(be)[t];
    float o0 = (v0 - mean) * rstd * gg.x + bb.x;
    float o1 = (v1 - mean) * rstd * gg.y + bb.y;
    float o2 = (v2 - mean) * rstd * gg.z + bb.z;
    float o3 = (v3 - mean) * rstd * gg.w + bb.w;
    float4 out = { o0, o1, o2, o3 };
    reinterpret_cast<float4*>(y + (size_t)row * 1024)[t] = out;
    if (yb) {
        ushort4 ob = { f2b(o0), f2b(o1), f2b(o2), f2b(o3) };
        reinterpret_cast<ushort4*>(yb + (size_t)row * 1024)[t] = ob;
    }
}

// ---- fused: f2 = gelu(sum 4 bf16 partials + b2); x = LN(f2 + h) ------------
// p0 holds splits 0,1 (stride apart); p2 holds splits 2,3.
__global__ __launch_bounds__(256) void ln_res_red4(const bf16* __restrict__ p0,
                                                   const bf16* __restrict__ p2,
                                                   const float* __restrict__ bias,
                                                   const float* __restrict__ r,
                                                   const float* __restrict__ g,
                                                   const float* __restrict__ be,
                                                   float* __restrict__ y,
                                                   bf16* __restrict__ yb,
                                                   size_t stride) {
    const int row = blockIdx.x, t = threadIdx.x;
    const size_t off = (size_t)row * 1024 + t * 4;
    float4 bb4 = reinterpret_cast<const float4*>(bias)[t];
    float s0 = bb4.x, s1v = bb4.y, s2v = bb4.z, s3 = bb4.w;
#pragma unroll
    for (int k = 0; k < 2; ++k) {
        ushort4 va = *reinterpret_cast<const ushort4*>(p0 + k * stride + off);
        s0 += b2f(va.x); s1v += b2f(va.y); s2v += b2f(va.z); s3 += b2f(va.w);
        ushort4 vb = *reinterpret_cast<const ushort4*>(p2 + k * stride + off);
        s0 += b2f(vb.x); s1v += b2f(vb.y); s2v += b2f(vb.z); s3 += b2f(vb.w);
    }
    float4 vr = reinterpret_cast<const float4*>(r + (size_t)row * 1024)[t];
    float v0 = gelu_fast(s0) + vr.x;
    float v1 = gelu_fast(s1v) + vr.y;
    float v2 = gelu_fast(s2v) + vr.z;
    float v3 = gelu_fast(s3) + vr.w;
    float s1 = v0 + v1 + v2 + v3;
    float s2 = v0 * v0 + v1 * v1 + v2 * v2 + v3 * v3;
#pragma unroll
    for (int m = 1; m < 64; m <<= 1) {
        s1 += __shfl_xor(s1, m, 64);
        s2 += __shfl_xor(s2, m, 64);
    }
    __shared__ float ws1[4], ws2[4];
    if ((t & 63) == 0) { ws1[t >> 6] = s1; ws2[t >> 6] = s2; }
    __syncthreads();
    s1 = ws1[0] + ws1[1] + ws1[2] + ws1[3];
    s2 = ws2[0] + ws2[1] + ws2[2] + ws2[3];
    const float mean = s1 * (1.f / 1024.f);
    const float var = s2 * (1.f / 1024.f) - mean * mean;
    const float rstd = rsqrtf(var + 1e-5f);
    float4 gg = reinterpret_cast<const float4*>(g)[t];
    float4 bb = reinterpret_cast<const float4*>(be)[t];
    float o0 = (v0 - mean) * rstd * gg.x + bb.x;
    float o1 = (v1 - mean) * rstd * gg.y + bb.y;
    float o2 = (v2 - mean) * rstd * gg.z + bb.z;
    float o3 = (v3 - mean) * rstd * gg.w + bb.w;
    float4 out = { o0, o1, o2, o3 };
    reinterpret_cast<float4*>(y + (size_t)row * 1024)[t] = out;
    ushort4 ob = { f2b(o0), f2b(o1), f2b(o2), f2b(o3) };
    reinterpret_cast<ushort4*>(yb + (size_t)row * 1024)[t] = ob;
}

// ---------------------------------------------------------------------------
extern "C" void kernel_launch(void* const* d_in, const int* in_sizes, int n_in,
                              void* d_out, int out_size, void* d_ws, size_t ws_size,
                              hipStream_t stream) {
    const float* x_in = (const float*)d_in[0];
    const float* Wqkv = (const float*)d_in[1];
    const float* bqkv = (const float*)d_in[2];
    const float* W1   = (const float*)d_in[3];
    const float* b1   = (const float*)d_in[4];
    const float* W2   = (const float*)d_in[5];
    const float* b2   = (const float*)d_in[6];
    const float* g1   = (const float*)d_in[7];
    const float* be1  = (const float*)d_in[8];
    const float* g2   = (const float*)d_in[9];
    const float* be2  = (const float*)d_in[10];

    const int Bv = 2, N = 2048, L = 4, Hh = 16;
    const int R = Bv * N;  // 4096 token rows

    char* p = (char*)d_ws;
    auto alloc = [&](size_t bytes) { char* r = p; p += (bytes + 255) & ~(size_t)255; return r; };
    bf16*  Wqkvt = (bf16*)alloc((size_t)L * 3072 * 1024 * 2);
    bf16*  W1t   = (bf16*)alloc((size_t)L * 4096 * 1024 * 2);
    bf16*  W2t   = (bf16*)alloc((size_t)L * 1024 * 4096 * 2);
    bf16*  xb    = (bf16*)alloc((size_t)R * 1024 * 2);
    bf16*  qkvb  = (bf16*)alloc((size_t)R * 3072 * 2);
    float* obuf  = (float*)alloc((size_t)R * 1024 * 4);
    float* hbuf  = (float*)alloc((size_t)R * 1024 * 4);
    bf16*  hb    = (bf16*)alloc((size_t)R * 1024 * 2);
    bf16*  f1b   = (bf16*)alloc((size_t)R * 4096 * 2);
    float* xcur  = (float*)alloc((size_t)R * 1024 * 4);
    bf16*  vtg   = (bf16*)hbuf;   // 8.4MB V^T; hbuf dead during qkv-gemm/attn
    // split-K bf16 partials: splits 0,1 -> obuf (16.78MB, dead after LN1 reads o);
    // splits 2,3 -> qkvb (dead after attn). Neither aliases xb/xcur/hbuf.
    bf16*  part0 = (bf16*)obuf;
    bf16*  part2 = (bf16*)qkvb;

    transpose_cast<<<dim3(3072 / 32, 1024 / 32, L), dim3(32, 8), 0, stream>>>(Wqkv, Wqkvt, 1024, 3072);
    transpose_cast<<<dim3(4096 / 32, 1024 / 32, L), dim3(32, 8), 0, stream>>>(W1, W1t, 1024, 4096);
    transpose_cast<<<dim3(1024 / 32, 4096 / 32, L), dim3(32, 8), 0, stream>>>(W2, W2t, 4096, 1024);
    cast_bf16_k<<<(R * 1024 / 4 + 255) / 256, 256, 0, stream>>>(x_in, xb, R * 1024 / 4);

    const float* xres = x_in;
    for (int l = 0; l < L; ++l) {
        // qkv = x @ Wqkv + bqkv; Q/K -> qkvb, V -> transposed vtg (fused vtrans)
        gemm256<4><<<(R / 256) * (3072 / 256), 512, 0, stream>>>(
            xb, Wqkvt + (size_t)l * 3072 * 1024, bqkv + l * 3072, qkvb, vtg,
            R, 3072, 1024, 3072 / 256, (R / 256) * (3072 / 256), 1024);
        // o = softmax(q k^T / 32) v   (QBLK=128, 512 blocks = 2/CU)
        attn_fwd<<<(N / 128) * (Bv * Hh), 256, 0, stream>>>(qkvb, vtg, obuf, N);
        // h = LN(o + x)   (overwrites vtg region -- attn already done)
        ln_res<<<R, 256, 0, stream>>>(obuf, xres, g1 + l * 1024, be1 + l * 1024, hbuf, hb);
        // f1 = gelu(h @ W1 + b1) -> bf16  (256x256 pipelined, 256 blocks)
        gemm256<1><<<(R / 256) * (4096 / 256), 512, 0, stream>>>(
            hb, W1t + (size_t)l * 4096 * 1024, b1 + l * 4096, f1b, nullptr,
            R, 4096, 1024, 4096 / 256, (R / 256) * (4096 / 256), 1024);
        // f2 partials: f1 @ W2 split-K=4 -> bf16 into part0 (s0,s1) / part2 (s2,s3)
        gemm256<3><<<(R / 256) * (1024 / 256) * 4, 512, 0, stream>>>(
            f1b, W2t + (size_t)l * 1024 * 4096, nullptr, part0, part2,
            R, 1024, 1024, 1024 / 256, (R / 256) * (1024 / 256), 4096);
        // x = LN(gelu(sum partials + b2) + h)  (fused reduce + LN2)
        float* xn = (l == L - 1) ? (float*)d_out : xcur;
        ln_res_red4<<<R, 256, 0, stream>>>(part0, part2, b2 + l * 1024, hbuf,
                                           g2 + l * 1024, be2 + l * 1024, xn, xb,
                                           (size_t)R * 1024);
        xres = xn;
    }
}